// Round 4
// baseline (4050.117 us; speedup 1.0000x reference)
//
#include <hip/hip_runtime.h>

// Problem constants
#define SEQ   2048
#define NBAT  2
#define MTOT  4096        // NBAT*SEQ
#define DIMC  1024
#define DFFC  4096
#define NEXP  8
#define NHEAD 16

typedef unsigned short u16;
typedef __attribute__((ext_vector_type(8)))  __bf16          bf16x8;
typedef __attribute__((ext_vector_type(8)))  unsigned short  us8;
typedef __attribute__((ext_vector_type(16))) float           f32x16;

// fp32 -> (hi, lo) bf16 split: a ~= hi + lo, residual ~2^-16 relative.
__device__ __forceinline__ void split2(float a, u16& h, u16& l)
{
  const unsigned ua = __float_as_uint(a);
  h = (u16)(ua >> 16);                               // truncated hi
  const float r = a - __uint_as_float(ua & 0xffff0000u);
  l = (u16)((__float_as_uint(r) + 0x8000u) >> 16);   // RN lo
}

__device__ __forceinline__ bf16x8 ld_frag(const u16* p)
{
  return __builtin_bit_cast(bf16x8, *(const us8*)p);
}

__device__ __forceinline__ f32x16 mfma32(bf16x8 a, bf16x8 b, f32x16 c)
{
  return __builtin_amdgcn_mfma_f32_32x32x16_bf16(a, b, c, 0, 0, 0);
}

// ===========================================================================
// FAST PATH: pre-split bf16 GEMM.  Tile 256x128, 4 waves (2x2), wave 128x64
// (mw=4, nf=2 fragments of 32x32x16).  A: M-rows x K; B: N-rows x K (both
// pre-split hi/lo bf16 row-major).  zmode: 0 none; 1 MoE1-pair (z=expert);
// 2 MoE2-quad (z=(par,kh)); 3 proj split-K2 (z=kh).
// ===========================================================================
template<bool WF32, bool WSPLIT>
__global__ __launch_bounds__(256, 2)
void psgemm_kernel(const u16* __restrict__ Ah, const u16* __restrict__ Al, int lda,
                   const u16* __restrict__ Bh, const u16* __restrict__ Bl, int ldb,
                   int K,
                   float* __restrict__ Cf, u16* __restrict__ Ch, u16* __restrict__ Cl,
                   int ldc,
                   const float* __restrict__ bias, const float* __restrict__ residual,
                   const float* __restrict__ row_scale, int rs_stride,
                   int do_relu, int do_accum,
                   int zmode, long sAZ, long sBZ, long sCZ, int sbias)
{
  const int z = blockIdx.z;
  if (zmode == 1) {
    Bh += (size_t)z * sBZ; Bl += (size_t)z * sBZ;
    if (bias) bias += (size_t)z * sbias;
    Ch += (size_t)z * sCZ; Cl += (size_t)z * sCZ;
  } else if (zmode == 2) {
    const int par = z >> 1, kh = z & 1;
    Ah += (size_t)par * sAZ + kh * 2048; Al += (size_t)par * sAZ + kh * 2048;
    Bh += (size_t)par * sBZ + kh * 2048; Bl += (size_t)par * sBZ + kh * 2048;
    Cf += (size_t)z * sCZ;
    row_scale += par;
    if (kh) bias += (size_t)par * sbias; else bias = nullptr;
  } else if (zmode == 3) {
    Ah += z * 512; Al += z * 512; Bh += z * 512; Bl += z * 512;
    Cf += (size_t)z * sCZ;
    if (!z) { bias = nullptr; residual = nullptr; }
  }

  __shared__ __align__(16) u16 As[2][4][256][8];   // 32 KB
  __shared__ __align__(16) u16 Bs[2][4][128][8];   // 16 KB
  const int t = threadIdx.x;
  const int m0 = blockIdx.y * 256, n0 = blockIdx.x * 128;
  const int wid = t >> 6, lane = t & 63;
  const int wr = wid >> 1, wc = wid & 1;
  const int l31 = lane & 31, lhi = lane >> 5;

  f32x16 acc[4][2];
#pragma unroll
  for (int i = 0; i < 4; ++i)
#pragma unroll
    for (int j = 0; j < 2; ++j)
#pragma unroll
      for (int r = 0; r < 16; ++r) acc[i][j][r] = 0.f;

  const u16* pAh = Ah + (size_t)(m0 + t) * lda;
  const u16* pAl = Al + (size_t)(m0 + t) * lda;
  const int brow = t >> 1, bkg = (t & 1) * 2, bko = (t & 1) * 16;
  const u16* pBh = Bh + (size_t)(n0 + brow) * ldb + bko;
  const u16* pBl = Bl + (size_t)(n0 + brow) * ldb + bko;

  for (int k0 = 0; k0 < K; k0 += 32) {
    __syncthreads();
#pragma unroll
    for (int q = 0; q < 4; ++q)
      *(us8*)&As[0][q][t][0] = *(const us8*)&pAh[k0 + q * 8];
#pragma unroll
    for (int q = 0; q < 4; ++q)
      *(us8*)&As[1][q][t][0] = *(const us8*)&pAl[k0 + q * 8];
#pragma unroll
    for (int q = 0; q < 2; ++q)
      *(us8*)&Bs[0][bkg + q][brow][0] = *(const us8*)&pBh[k0 + q * 8];
#pragma unroll
    for (int q = 0; q < 2; ++q)
      *(us8*)&Bs[1][bkg + q][brow][0] = *(const us8*)&pBl[k0 + q * 8];
    __syncthreads();

#pragma unroll
    for (int ks = 0; ks < 2; ++ks) {
      const int kg = ks * 2 + lhi;
      bf16x8 ah[4], al[4], bh[2], bl[2];
#pragma unroll
      for (int mf = 0; mf < 4; ++mf) {
        ah[mf] = ld_frag(&As[0][kg][wr * 128 + mf * 32 + l31][0]);
        al[mf] = ld_frag(&As[1][kg][wr * 128 + mf * 32 + l31][0]);
      }
#pragma unroll
      for (int nf = 0; nf < 2; ++nf) {
        bh[nf] = ld_frag(&Bs[0][kg][wc * 64 + nf * 32 + l31][0]);
        bl[nf] = ld_frag(&Bs[1][kg][wc * 64 + nf * 32 + l31][0]);
      }
#pragma unroll
      for (int mf = 0; mf < 4; ++mf)
#pragma unroll
        for (int nf = 0; nf < 2; ++nf) {
          acc[mf][nf] = mfma32(al[mf], bh[nf], acc[mf][nf]);
          acc[mf][nf] = mfma32(ah[mf], bl[nf], acc[mf][nf]);
          acc[mf][nf] = mfma32(ah[mf], bh[nf], acc[mf][nf]);
        }
    }
  }

  // epilogue: C/D layout col=lane&31, row=(r&3)+8*(r>>2)+4*lhi  (verified)
#pragma unroll
  for (int mf = 0; mf < 4; ++mf)
#pragma unroll
    for (int nf = 0; nf < 2; ++nf) {
      const int col = n0 + wc * 64 + nf * 32 + l31;
      const float bia = bias ? bias[col] : 0.f;
#pragma unroll
      for (int r = 0; r < 16; ++r) {
        const int row = m0 + wr * 128 + mf * 32 + (r & 3) + 8 * (r >> 2) + 4 * lhi;
        float v = acc[mf][nf][r] + bia;
        if (do_relu) v = fmaxf(v, 0.f);
        if (row_scale) v *= row_scale[(size_t)row * rs_stride];
        if (residual) v += residual[(size_t)row * ldc + col];
        if (WF32) {
          float* cp = &Cf[(size_t)row * ldc + col];
          float vv = v;
          if (do_accum) vv += *cp;
          *cp = vv;
        }
        if (WSPLIT) {
          u16 h, l; split2(v, h, l);
          Ch[(size_t)row * ldc + col] = h;
          Cl[(size_t)row * ldc + col] = l;
        }
      }
    }
}

// ---------------------------------------------------------------------------
// Conversion kernels (fast path)
// ---------------------------------------------------------------------------
// straight split: fp32[n4*4] -> hi/lo bf16
__global__ __launch_bounds__(256)
void split_rows_kernel(const float* __restrict__ in, u16* __restrict__ oh,
                       u16* __restrict__ ol, long n4)
{
  const long g = (long)blockIdx.x * 256 + threadIdx.x;
  if (g >= n4) return;
  const float4 v = *(const float4*)&in[g * 4];
  union { u16 s[4]; unsigned long long v64; } ph, pl;
  split2(v.x, ph.s[0], pl.s[0]); split2(v.y, ph.s[1], pl.s[1]);
  split2(v.z, ph.s[2], pl.s[2]); split2(v.w, ph.s[3], pl.s[3]);
  *(unsigned long long*)&oh[g * 4] = ph.v64;
  *(unsigned long long*)&ol[g * 4] = pl.v64;
}

// transpose + split: in (R,C) fp32 row-major -> out (C,R) hi/lo bf16.
// grid (C/32, R/32, E), block (32,8)
__global__ __launch_bounds__(256)
void split_T_kernel(const float* __restrict__ in, u16* __restrict__ oh,
                    u16* __restrict__ ol, int R, int C)
{
  __shared__ float tile[32][33];
  const size_t zo = (size_t)blockIdx.z * R * C;
  in += zo; oh += zo; ol += zo;
  const int tx = threadIdx.x, ty = threadIdx.y;
  const int r0 = blockIdx.y * 32, c0 = blockIdx.x * 32;
#pragma unroll
  for (int i = 0; i < 4; ++i)
    tile[ty + i * 8][tx] = in[(size_t)(r0 + ty + i * 8) * C + c0 + tx];
  __syncthreads();
#pragma unroll
  for (int i = 0; i < 4; ++i) {
    const float v = tile[tx][ty + i * 8];
    u16 h, l; split2(v, h, l);
    const size_t o = (size_t)(c0 + ty + i * 8) * R + r0 + tx;
    oh[o] = h; ol[o] = l;
  }
}

// im2col + split: col[m][tt*1024+i] = x[b, s+tt-1, i]
__global__ __launch_bounds__(256)
void im2cs_kernel(const float* __restrict__ x, u16* __restrict__ oh,
                  u16* __restrict__ ol)
{
  const long g = (long)blockIdx.x * 256 + threadIdx.x;   // < 4096*3072/4
  if (g >= (long)MTOT * 3072 / 4) return;
  const long id4 = g * 4;
  const int j = (int)(id4 % 3072);
  const int m = (int)(id4 / 3072);
  const int tt = j >> 10, i = j & 1023;
  const int b = m >> 11, s = m & 2047;
  const int sr = s + tt - 1;
  float4 v = make_float4(0.f, 0.f, 0.f, 0.f);
  if (sr >= 0 && sr < SEQ) v = *(const float4*)&x[((size_t)(b * SEQ + sr) << 10) + i];
  union { u16 s[4]; unsigned long long v64; } ph, pl;
  split2(v.x, ph.s[0], pl.s[0]); split2(v.y, ph.s[1], pl.s[1]);
  split2(v.z, ph.s[2], pl.s[2]); split2(v.w, ph.s[3], pl.s[3]);
  *(unsigned long long*)&oh[id4] = ph.v64;
  *(unsigned long long*)&ol[id4] = pl.v64;
}

// conv weight pack + split: out[o][tt*1024+i] = cw[o][i][tt]  (N-rows x K)
__global__ __launch_bounds__(256)
void wpks_kernel(const float* __restrict__ cw, u16* __restrict__ oh,
                 u16* __restrict__ ol)
{
  const long g = (long)blockIdx.x * 256 + threadIdx.x;   // < 1024*3072/4
  if (g >= (long)1024 * 3072 / 4) return;
  const long id4 = g * 4;
  const int o = (int)(id4 / 3072);
  const int kp = (int)(id4 % 3072);
  const int tt = kp >> 10, i = kp & 1023;
  union { u16 s[4]; unsigned long long v64; } ph, pl;
#pragma unroll
  for (int q = 0; q < 4; ++q) {
    const float v = cw[(size_t)o * 3072 + (i + q) * 3 + tt];
    split2(v, ph.s[q], pl.s[q]);
  }
  *(unsigned long long*)&oh[id4] = ph.v64;
  *(unsigned long long*)&ol[id4] = pl.v64;
}

// ===========================================================================
// FALLBACK: round-3 in-kernel-split GEMM (proven at 3919 us)
// ===========================================================================
__device__ __forceinline__ void stage_rows_f32(const float* __restrict__ src0, size_t ld,
                                               int t, u16 (*dst)[4][128][8])
{
  const int row = t >> 1, ks = (t & 1) * 16;
  const float* src = src0 + (size_t)row * ld + ks;
#pragma unroll
  for (int q = 0; q < 4; ++q) {
    const float4 v = *(const float4*)&src[q * 4];
    const int kk = ks + q * 4;
    const int kg = kk >> 3, j0 = kk & 7;
    union { u16 s[4]; unsigned long long v64; } ph, pl;
    split2(v.x, ph.s[0], pl.s[0]); split2(v.y, ph.s[1], pl.s[1]);
    split2(v.z, ph.s[2], pl.s[2]); split2(v.w, ph.s[3], pl.s[3]);
    *(unsigned long long*)&dst[0][kg][row][j0] = ph.v64;
    *(unsigned long long*)&dst[1][kg][row][j0] = pl.v64;
  }
}

template<bool BT>
__global__ __launch_bounds__(256)
void mgemm_kernel(const float* __restrict__ Ag, const float* __restrict__ Bg,
                  float* __restrict__ C, int K, int lda, int ldb, int ldc,
                  const float* __restrict__ bias,
                  const float* __restrict__ residual,
                  const float* __restrict__ row_scale, int rs_stride,
                  int do_relu, int do_accum)
{
  __shared__ __align__(16) u16 As[2][4][128][8];
  __shared__ __align__(16) u16 Bs[2][4][128][8];
  const int t  = threadIdx.x;
  const int m0 = blockIdx.y * 128;
  const int n0 = blockIdx.x * 128;
  const int wid = t >> 6, lane = t & 63;
  const int wr = wid >> 1, wc = wid & 1;
  const int l31 = lane & 31, lhi = lane >> 5;

  f32x16 acc[2][2];
#pragma unroll
  for (int i = 0; i < 2; ++i)
#pragma unroll
    for (int j = 0; j < 2; ++j)
#pragma unroll
      for (int r = 0; r < 16; ++r) acc[i][j][r] = 0.f;

  for (int k0 = 0; k0 < K; k0 += 32) {
    __syncthreads();
    stage_rows_f32(&Ag[(size_t)m0 * lda + k0], lda, t, As);
    if (BT) {
      stage_rows_f32(&Bg[(size_t)n0 * ldb + k0], ldb, t, Bs);
    } else {
      const int col = t & 127, kh = t >> 7;
      const float* src = &Bg[(size_t)(k0 + kh * 16) * ldb + n0 + col];
      float vv[16];
#pragma unroll
      for (int kk = 0; kk < 16; ++kk) vv[kk] = src[(size_t)kk * ldb];
#pragma unroll
      for (int q = 0; q < 4; ++q) {
        const int kg = kh * 2 + (q >> 1);
        const int j0 = (q & 1) * 4;
        union { u16 s[4]; unsigned long long v64; } ph, pl;
#pragma unroll
        for (int i = 0; i < 4; ++i) split2(vv[q * 4 + i], ph.s[i], pl.s[i]);
        *(unsigned long long*)&Bs[0][kg][col][j0] = ph.v64;
        *(unsigned long long*)&Bs[1][kg][col][j0] = pl.v64;
      }
    }
    __syncthreads();

#pragma unroll
    for (int ks = 0; ks < 2; ++ks) {
      bf16x8 ah[2], al[2], bh[2], bl[2];
#pragma unroll
      for (int f = 0; f < 2; ++f) {
        ah[f] = ld_frag(&As[0][ks * 2 + lhi][wr * 64 + f * 32 + l31][0]);
        al[f] = ld_frag(&As[1][ks * 2 + lhi][wr * 64 + f * 32 + l31][0]);
        bh[f] = ld_frag(&Bs[0][ks * 2 + lhi][wc * 64 + f * 32 + l31][0]);
        bl[f] = ld_frag(&Bs[1][ks * 2 + lhi][wc * 64 + f * 32 + l31][0]);
      }
#pragma unroll
      for (int mf = 0; mf < 2; ++mf)
#pragma unroll
        for (int nf = 0; nf < 2; ++nf) {
          acc[mf][nf] = mfma32(al[mf], bh[nf], acc[mf][nf]);
          acc[mf][nf] = mfma32(ah[mf], bl[nf], acc[mf][nf]);
          acc[mf][nf] = mfma32(ah[mf], bh[nf], acc[mf][nf]);
        }
    }
  }

#pragma unroll
  for (int mf = 0; mf < 2; ++mf)
#pragma unroll
    for (int nf = 0; nf < 2; ++nf) {
      const int cn  = n0 + wc * 64 + nf * 32 + l31;
      const float bia = bias ? bias[cn] : 0.f;
#pragma unroll
      for (int r = 0; r < 16; ++r) {
        const int row = m0 + wr * 64 + mf * 32 + (r & 3) + 8 * (r >> 2) + 4 * lhi;
        float v = acc[mf][nf][r] + bia;
        if (do_relu)   v = fmaxf(v, 0.f);
        if (row_scale) v *= row_scale[(size_t)row * rs_stride];
        if (residual)  v += residual[(size_t)row * ldc + cn];
        float* cp = &C[(size_t)row * ldc + cn];
        if (do_accum)  v += *cp;
        *cp = v;
      }
    }
}

__global__ __launch_bounds__(256)
void wpack_kernel(const float* __restrict__ cw, float* __restrict__ wp)
{
  const int idx = blockIdx.x * 256 + threadIdx.x;
  if (idx >= 3072 * 1024) return;
  const int o  = idx & 1023;
  const int k  = idx >> 10;
  const int tt = k >> 10;
  const int i  = k & 1023;
  wp[idx] = cw[(size_t)o * 3072 + i * 3 + tt];
}

__global__ __launch_bounds__(256)
void im2col_kernel(const float* __restrict__ x, float* __restrict__ col)
{
  const size_t idx = (size_t)blockIdx.x * 256 + threadIdx.x;
  if (idx >= (size_t)MTOT * 3072) return;
  const int j  = (int)(idx % 3072);
  const int m  = (int)(idx / 3072);
  const int tt = j >> 10;
  const int i  = j & 1023;
  const int b  = m >> 11;
  const int s  = m & 2047;
  const int sr = s + tt - 1;
  float v = 0.f;
  if (sr >= 0 && sr < SEQ) v = x[((size_t)(b * SEQ + sr) << 10) + i];
  col[idx] = v;
}

// ---------------------------------------------------------------------------
// Fused flash-style attention, fp32 compute.  SPLIT=1: write split-bf16 ctx.
// ---------------------------------------------------------------------------
template<bool SPLIT>
__global__ __launch_bounds__(256)
void attn_kernel(const float* __restrict__ qkv, float* __restrict__ ctxf,
                 u16* __restrict__ ctxh, u16* __restrict__ ctxl)
{
  const int qt = blockIdx.x, h = blockIdx.y, b = blockIdx.z;
  const int t = threadIdx.x;
  const int lane = t & 63;
  const int qr = t >> 2, quad = t & 3;
  __shared__ float Ks[64 * 64];
  __shared__ float Vs[64 * 64];
  const size_t base = (size_t)b * SEQ * 3072;
  const int hoff = h * 64;

  float4 qreg[16];
  {
    const float* qrow = &qkv[base + (size_t)(qt * 64 + qr) * 3072 + hoff];
#pragma unroll
    for (int d4 = 0; d4 < 16; ++d4) qreg[d4] = *(const float4*)&qrow[d4 * 4];
  }

  float m_run = -1e30f, l_run = 0.f;
  float4 ctx4[4];
#pragma unroll
  for (int j = 0; j < 4; ++j) ctx4[j] = make_float4(0.f, 0.f, 0.f, 0.f);

  for (int kt = 0; kt < SEQ / 64; ++kt) {
    __syncthreads();
    for (int i = t; i < 64 * 16; i += 256) {
      const int r  = i >> 4;
      const int c4 = i & 15;
      const int cs = c4 ^ ((r >> 4) << 2);
      const float* src = &qkv[base + (size_t)(kt * 64 + r) * 3072 + 1024 + hoff + c4 * 4];
      *(float4*)&Ks[r * 64 + cs * 4] = *(const float4*)src;
      *(float4*)&Vs[r * 64 + cs * 4] = *(const float4*)&src[1024];
    }
    __syncthreads();

    float p[16];
    float tmax = -1e30f;
#pragma unroll
    for (int kk = 0; kk < 16; ++kk) {
      const int k = quad * 16 + kk;
      const float* krow = &Ks[k * 64];
      const int sw = (k >> 4) << 2;
      float a = 0.f;
#pragma unroll
      for (int d4 = 0; d4 < 16; ++d4) {
        const float4 kv = *(const float4*)&krow[(d4 ^ sw) * 4];
        a = __builtin_fmaf(qreg[d4].x, kv.x, a);
        a = __builtin_fmaf(qreg[d4].y, kv.y, a);
        a = __builtin_fmaf(qreg[d4].z, kv.z, a);
        a = __builtin_fmaf(qreg[d4].w, kv.w, a);
      }
      p[kk] = a * 0.125f;
      tmax = fmaxf(tmax, p[kk]);
    }
    tmax = fmaxf(tmax, __shfl_xor(tmax, 1, 64));
    tmax = fmaxf(tmax, __shfl_xor(tmax, 2, 64));
    const float m_new = fmaxf(m_run, tmax);
    const float resc  = __expf(m_run - m_new);
    float l_tile = 0.f;
#pragma unroll
    for (int kk = 0; kk < 16; ++kk) { p[kk] = __expf(p[kk] - m_new); l_tile += p[kk]; }
    l_tile += __shfl_xor(l_tile, 1, 64);
    l_tile += __shfl_xor(l_tile, 2, 64);
    l_run = l_run * resc + l_tile;
    m_run = m_new;
#pragma unroll
    for (int j = 0; j < 4; ++j) {
      ctx4[j].x *= resc; ctx4[j].y *= resc; ctx4[j].z *= resc; ctx4[j].w *= resc;
    }
#pragma unroll
    for (int sq = 0; sq < 4; ++sq) {
#pragma unroll
      for (int kk = 0; kk < 16; ++kk) {
        const int k = sq * 16 + kk;
        const float pv = __shfl(p[kk], (lane & ~3) | sq, 64);
        const float* vrow = &Vs[k * 64];
        const int sw = (k >> 4) << 2;
#pragma unroll
        for (int j = 0; j < 4; ++j) {
          const int c4 = (quad * 4 + j) ^ sw;
          const float4 vv = *(const float4*)&vrow[c4 * 4];
          ctx4[j].x = __builtin_fmaf(pv, vv.x, ctx4[j].x);
          ctx4[j].y = __builtin_fmaf(pv, vv.y, ctx4[j].y);
          ctx4[j].z = __builtin_fmaf(pv, vv.z, ctx4[j].z);
          ctx4[j].w = __builtin_fmaf(pv, vv.w, ctx4[j].w);
        }
      }
    }
  }
  const float inv_l = 1.f / l_run;
  const size_t obase = (size_t)((size_t)b * SEQ + qt * 64 + qr) * 1024 + hoff + quad * 16;
#pragma unroll
  for (int j = 0; j < 4; ++j) {
    float4 o = ctx4[j];
    o.x *= inv_l; o.y *= inv_l; o.z *= inv_l; o.w *= inv_l;
    if (SPLIT) {
      union { u16 s[4]; unsigned long long v64; } ph, pl;
      split2(o.x, ph.s[0], pl.s[0]); split2(o.y, ph.s[1], pl.s[1]);
      split2(o.z, ph.s[2], pl.s[2]); split2(o.w, ph.s[3], pl.s[3]);
      *(unsigned long long*)&ctxh[obase + j * 4] = ph.v64;
      *(unsigned long long*)&ctxl[obase + j * 4] = pl.v64;
    } else {
      *(float4*)&ctxf[obase + j * 4] = o;
    }
  }
}

// ---------------------------------------------------------------------------
// LayerNorm: out = LN(in + r1 + r2 + r3 + r4) * g + b; optional split-out.
// ---------------------------------------------------------------------------
__global__ __launch_bounds__(256)
void ln_kernel(const float* __restrict__ in, const float* __restrict__ r1,
               const float* __restrict__ r2, const float* __restrict__ r3,
               const float* __restrict__ r4,
               const float* __restrict__ g, const float* __restrict__ bt,
               float* __restrict__ outf, u16* __restrict__ outh, u16* __restrict__ outl)
{
  const int row = blockIdx.x, t = threadIdx.x;
  const size_t off = ((size_t)row << 10) + t * 4;
  float4 v = *(const float4*)&in[off];
  if (r1) { const float4 r = *(const float4*)&r1[off]; v.x += r.x; v.y += r.y; v.z += r.z; v.w += r.w; }
  if (r2) { const float4 r = *(const float4*)&r2[off]; v.x += r.x; v.y += r.y; v.z += r.z; v.w += r.w; }
  if (r3) { const float4 r = *(const float4*)&r3[off]; v.x += r.x; v.y += r.y; v.z += r.z; v.w += r.w; }
  if (r4) { const float4 r = *(const float4*)&r4[off]; v.x += r.x; v.y += r.y; v.z += r.z; v.w += r.w; }
  float s  = v.x + v.y + v.z + v.w;
  float ss = v.x * v.x + v.y * v.y + v.z * v.z + v.w * v.w;
#pragma unroll
  for (int o = 32; o; o >>= 1) {
    s  += __shfl_xor(s, o, 64);
    ss += __shfl_xor(ss, o, 64);
  }
  __shared__ float red[8];
  if ((t & 63) == 0) { red[(t >> 6) * 2] = s; red[(t >> 6) * 2 + 1] = ss; }
  __syncthreads();
  s  = red[0] + red[2] + red[4] + red[6];
  ss = red[1] + red[3] + red[5] + red[7];
  const float mu   = s * (1.f / 1024.f);
  const float var  = ss * (1.f / 1024.f) - mu * mu;
  const float rstd = rsqrtf(var + 1e-5f);
  const float4 gg = *(const float4*)&g[t * 4];
  const float4 bb = *(const float4*)&bt[t * 4];
  float4 o;
  o.x = (v.x - mu) * rstd * gg.x + bb.x;
  o.y = (v.y - mu) * rstd * gg.y + bb.y;
  o.z = (v.z - mu) * rstd * gg.z + bb.z;
  o.w = (v.w - mu) * rstd * gg.w + bb.w;
  if (outf) *(float4*)&outf[off] = o;
  if (outh) {
    union { u16 s[4]; unsigned long long v64; } ph, pl;
    split2(o.x, ph.s[0], pl.s[0]); split2(o.y, ph.s[1], pl.s[1]);
    split2(o.z, ph.s[2], pl.s[2]); split2(o.w, ph.s[3], pl.s[3]);
    *(unsigned long long*)&outh[off] = ph.v64;
    *(unsigned long long*)&outl[off] = pl.v64;
  }
}

// ---------------------------------------------------------------------------
// MoE gate: probs[m, 0..7] = softmax(x[m,:] @ gate_w + gate_b). 1 wave / row.
// ---------------------------------------------------------------------------
__global__ __launch_bounds__(64)
void gate_kernel(const float* __restrict__ x, const float* __restrict__ gw,
                 const float* __restrict__ gb, float* __restrict__ probs)
{
  const int m = blockIdx.x, lane = threadIdx.x;
  float acc[8];
#pragma unroll
  for (int e = 0; e < 8; ++e) acc[e] = 0.f;
  for (int k = lane; k < 1024; k += 64) {
    const float xv = x[((size_t)m << 10) + k];
    const float4 g0 = *(const float4*)&gw[k * 8];
    const float4 g1 = *(const float4*)&gw[k * 8 + 4];
    acc[0] = __builtin_fmaf(xv, g0.x, acc[0]);
    acc[1] = __builtin_fmaf(xv, g0.y, acc[1]);
    acc[2] = __builtin_fmaf(xv, g0.z, acc[2]);
    acc[3] = __builtin_fmaf(xv, g0.w, acc[3]);
    acc[4] = __builtin_fmaf(xv, g1.x, acc[4]);
    acc[5] = __builtin_fmaf(xv, g1.y, acc[5]);
    acc[6] = __builtin_fmaf(xv, g1.z, acc[6]);
    acc[7] = __builtin_fmaf(xv, g1.w, acc[7]);
  }
#pragma unroll
  for (int o = 32; o; o >>= 1)
#pragma unroll
    for (int e = 0; e < 8; ++e) acc[e] += __shfl_xor(acc[e], o, 64);
  float lg[8], mx = -1e30f;
#pragma unroll
  for (int e = 0; e < 8; ++e) { lg[e] = acc[e] + gb[e]; mx = fmaxf(mx, lg[e]); }
  float se = 0.f;
#pragma unroll
  for (int e = 0; e < 8; ++e) { lg[e] = __expf(lg[e] - mx); se += lg[e]; }
  const float inv = 1.f / se;
  if (lane < 8) probs[(size_t)m * 8 + lane] = lg[lane] * inv;
}

// ---------------------------------------------------------------------------
extern "C" void kernel_launch(void* const* d_in, const int* in_sizes, int n_in,
                              void* d_out, int out_size, void* d_ws, size_t ws_size,
                              hipStream_t stream)
{
  const float* x      = (const float*)d_in[0];
  const float* conv_w = (const float*)d_in[1];
  const float* conv_b = (const float*)d_in[2];
  const float* wqkv   = (const float*)d_in[3];
  const float* bqkv   = (const float*)d_in[4];
  const float* wo     = (const float*)d_in[5];
  const float* bo     = (const float*)d_in[6];
  const float* ln1_g  = (const float*)d_in[7];
  const float* ln1_b  = (const float*)d_in[8];
  const float* gate_w = (const float*)d_in[9];
  const float* gate_b = (const float*)d_in[10];
  const float* w1     = (const float*)d_in[11];
  const float* b1     = (const float*)d_in[12];
  const float* w2     = (const float*)d_in[13];
  const float* b2     = (const float*)d_in[14];
  const float* ln2_g  = (const float*)d_in[15];
  const float* ln2_b  = (const float*)d_in[16];
  float* out = (float*)d_out;

  const dim3 blk256(256);
  char* W = (char*)d_ws;
#define MB(x) ((size_t)(x) << 20)
  const size_t NEED_FAST = MB(481);

  if (ws_size >= NEED_FAST) {
    // ---------------- FAST PATH (pre-split bf16) ----------------
    float* x1_f   = (float*)(W + MB(0));     // 16 MiB
    float* moe_f  = (float*)(W + MB(16));    // 4 x 16 MiB
    float* probs  = (float*)(W + MB(80));
    u16* x1s_h    = (u16*)(W + MB(81));
    u16* x1s_l    = (u16*)(W + MB(89));
    // Slot H [97,225): hbs later; early staging tenants
    u16* hbs_h    = (u16*)(W + MB(97));      // + z*33554432 elems
    u16* hbs_l    = (u16*)(W + MB(129));
    u16* im2cs_h  = (u16*)(W + MB(97));
    u16* im2cs_l  = (u16*)(W + MB(121));
    u16* wpks_h   = (u16*)(W + MB(145));
    u16* wpks_l   = (u16*)(W + MB(151));
    u16* ctxs_h   = (u16*)(W + MB(157));
    u16* ctxs_l   = (u16*)(W + MB(165));
    u16* wos_h    = (u16*)(W + MB(173));
    u16* wos_l    = (u16*)(W + MB(175));
    float* res1a  = (float*)(W + MB(177));
    float* res1b  = (float*)(W + MB(193));
    // Slot W1 [225,353): w1s later; early qkv/yconv
    u16* w1s_h    = (u16*)(W + MB(225));
    u16* w1s_l    = (u16*)(W + MB(289));
    float* qkv_f  = (float*)(W + MB(225));
    float* yconv_f= (float*)(W + MB(273));
    u16* yconvs_h = (u16*)(W + MB(289));
    u16* yconvs_l = (u16*)(W + MB(297));
    // Slot W2 [353,481): w2s later; early wqkvs
    u16* w2s_h    = (u16*)(W + MB(353));
    u16* w2s_l    = (u16*)(W + MB(417));
    u16* wqkvs_h  = (u16*)(W + MB(353));
    u16* wqkvs_l  = (u16*)(W + MB(359));

    // 1) conv staging (split) + conv GEMM -> yconv (f32 + split)
    im2cs_kernel<<<dim3(12288), blk256, 0, stream>>>(x, im2cs_h, im2cs_l);
    wpks_kernel<<<dim3(3072), blk256, 0, stream>>>(conv_w, wpks_h, wpks_l);
    psgemm_kernel<true, true><<<dim3(8, 16, 1), blk256, 0, stream>>>(
        im2cs_h, im2cs_l, 3072, wpks_h, wpks_l, 3072, 3072,
        yconv_f, yconvs_h, yconvs_l, 1024,
        conv_b, nullptr, nullptr, 0, 0, 0, 0, 0, 0, 0, 0);

    // 2) QKV
    split_rows_kernel<<<dim3(3072), blk256, 0, stream>>>(wqkv, wqkvs_h, wqkvs_l, 786432);
    psgemm_kernel<true, false><<<dim3(24, 16, 1), blk256, 0, stream>>>(
        yconvs_h, yconvs_l, 1024, wqkvs_h, wqkvs_l, 1024, 1024,
        qkv_f, nullptr, nullptr, 3072,
        bqkv, nullptr, nullptr, 0, 0, 0, 0, 0, 0, 0, 0);

    // 3) w2 convert (after qkv GEMM; overwrites wqkvs)
    split_T_kernel<<<dim3(32, 128, 8), dim3(32, 8), 0, stream>>>(w2, w2s_h, w2s_l, 4096, 1024);

    // 4) attention -> ctx split
    attn_kernel<true><<<dim3(SEQ / 64, NHEAD, NBAT), blk256, 0, stream>>>(
        qkv_f, nullptr, ctxs_h, ctxs_l);

    // 5) out projection split-K2 -> res1a/res1b (bias+residual on slice 1)
    split_rows_kernel<<<dim3(1024), blk256, 0, stream>>>(wo, wos_h, wos_l, 262144);
    psgemm_kernel<true, false><<<dim3(8, 16, 2), blk256, 0, stream>>>(
        ctxs_h, ctxs_l, 1024, wos_h, wos_l, 1024, 512,
        res1a, nullptr, nullptr, 1024,
        bo, yconv_f, nullptr, 0, 0, 0, 3, 0, 0, 4194304, 0);

    // 6) w1 convert (after proj; overwrites qkv/yconv)
    split_T_kernel<<<dim3(128, 32, 8), dim3(32, 8), 0, stream>>>(w1, w1s_h, w1s_l, 1024, 4096);

    // 7) LN1 -> x1 (f32 + split)
    ln_kernel<<<dim3(MTOT), blk256, 0, stream>>>(
        res1a, res1b, nullptr, nullptr, nullptr, ln1_g, ln1_b, x1_f, x1s_h, x1s_l);

    // 8) gate
    gate_kernel<<<dim3(MTOT), dim3(64), 0, stream>>>(x1_f, gate_w, gate_b, probs);

    // 9) MoE: expert pairs; MoE1 pair -> hbs split; MoE2 quad -> moe[0..3]
    for (int p = 0; p < 4; ++p) {
      const int e0 = 2 * p;
      psgemm_kernel<false, true><<<dim3(32, 16, 2), blk256, 0, stream>>>(
          x1s_h, x1s_l, 1024,
          w1s_h + (size_t)e0 * 4194304, w1s_l + (size_t)e0 * 4194304, 1024, 1024,
          nullptr, hbs_h, hbs_l, 4096,
          b1 + (size_t)e0 * 4096, nullptr, nullptr, 0, 1 /*relu*/, 0,
          1, 0, 4194304, 33554432, 4096);
      psgemm_kernel<true, false><<<dim3(8, 16, 4), blk256, 0, stream>>>(
          hbs_h, hbs_l, 4096,
          w2s_h + (size_t)e0 * 4194304, w2s_l + (size_t)e0 * 4194304, 4096, 2048,
          moe_f, nullptr, nullptr, 1024,
          b2 + (size_t)e0 * 1024, nullptr, probs + e0, 8, 0, (p > 0),
          2, 33554432, 4194304, 4194304, 1024);
    }

    // 10) LN2(x1 + moe0..3) -> out
    ln_kernel<<<dim3(MTOT), blk256, 0, stream>>>(
        x1_f, moe_f, moe_f + 4194304, moe_f + 8388608, moe_f + 12582912,
        ln2_g, ln2_b, out, nullptr, nullptr);
  } else {
    // ---------------- FALLBACK (round-3 path, 118 MB) ----------------
    float* ws = (float*)d_ws;
    float* A = ws;
    float* B = ws + 16777216;
    float* probs = B + 12582912;
    float* im2c  = A;
    float* yconv = A + 12582912;
    float* ctxb  = A;
    float* hbuf  = A;
    float* wpk   = B;
    float* qkvb  = B;
    float* res1  = B;
    float* x1    = B + 4194304;
    float* moe   = B + 8388608;

    wpack_kernel<<<dim3((3072 * 1024 + 255) / 256), blk256, 0, stream>>>(conv_w, wpk);
    im2col_kernel<<<dim3((MTOT * 3072 + 255) / 256), blk256, 0, stream>>>(x, im2c);
    mgemm_kernel<false><<<dim3(1024 / 128, MTOT / 128), blk256, 0, stream>>>(
        im2c, wpk, yconv, 3072, 3072, 1024, 1024,
        conv_b, nullptr, nullptr, 0, 0, 0);
    mgemm_kernel<true><<<dim3(3072 / 128, MTOT / 128), blk256, 0, stream>>>(
        yconv, wqkv, qkvb, 1024, 1024, 1024, 3072,
        bqkv, nullptr, nullptr, 0, 0, 0);
    attn_kernel<false><<<dim3(SEQ / 64, NHEAD, NBAT), blk256, 0, stream>>>(
        qkvb, ctxb, nullptr, nullptr);
    mgemm_kernel<true><<<dim3(1024 / 128, MTOT / 128), blk256, 0, stream>>>(
        ctxb, wo, res1, 1024, 1024, 1024, 1024,
        bo, yconv, nullptr, 0, 0, 0);
    ln_kernel<<<dim3(MTOT), blk256, 0, stream>>>(
        res1, nullptr, nullptr, nullptr, nullptr, ln1_g, ln1_b, x1, nullptr, nullptr);
    gate_kernel<<<dim3(MTOT), dim3(64), 0, stream>>>(x1, gate_w, gate_b, probs);
    for (int e = 0; e < NEXP; ++e) {
      const float* w1e = w1 + (size_t)e * DIMC * DFFC;
      const float* b1e = b1 + (size_t)e * DFFC;
      const float* w2e = w2 + (size_t)e * DFFC * DIMC;
      const float* b2e = b2 + (size_t)e * DIMC;
      mgemm_kernel<false><<<dim3(DFFC / 128, MTOT / 128), blk256, 0, stream>>>(
          x1, w1e, hbuf, 1024, 1024, DFFC, DFFC,
          b1e, nullptr, nullptr, 0, 1, 0);
      mgemm_kernel<false><<<dim3(DIMC / 128, MTOT / 128), blk256, 0, stream>>>(
          hbuf, w2e, moe, DFFC, DFFC, 1024, 1024,
          b2e, nullptr, probs + e, NEXP, 0, e > 0);
    }
    ln_kernel<<<dim3(MTOT), blk256, 0, stream>>>(
        x1, moe, nullptr, nullptr, nullptr, ln2_g, ln2_b, out, nullptr, nullptr);
  }
#undef MB
}

// Round 5
// 2956.512 us; speedup vs baseline: 1.3699x; 1.3699x over previous
//
#include <hip/hip_runtime.h>

// Problem constants
#define SEQ   2048
#define NBAT  2
#define MTOT  4096        // NBAT*SEQ
#define DIMC  1024
#define DFFC  4096
#define NEXP  8
#define NHEAD 16

typedef unsigned short u16;
typedef unsigned int   u32;
typedef unsigned long long u64;
typedef __attribute__((ext_vector_type(8)))  __bf16          bf16x8;
typedef __attribute__((ext_vector_type(8)))  unsigned short  us8;
typedef __attribute__((ext_vector_type(16))) float           f32x16;

// fp32 -> (hi, lo) bf16 split: a ~= hi + lo, residual ~2^-16 relative.
__device__ __forceinline__ void split2(float a, u16& h, u16& l)
{
  const unsigned ua = __float_as_uint(a);
  h = (u16)(ua >> 16);                               // truncated hi
  const float r = a - __uint_as_float(ua & 0xffff0000u);
  l = (u16)((__float_as_uint(r) + 0x8000u) >> 16);   // RN lo
}

__device__ __forceinline__ bf16x8 ld_frag(const u16* p)
{
  return __builtin_bit_cast(bf16x8, *(const us8*)p);
}

__device__ __forceinline__ f32x16 mfma32(bf16x8 a, bf16x8 b, f32x16 c)
{
  return __builtin_amdgcn_mfma_f32_32x32x16_bf16(a, b, c, 0, 0, 0);
}

// ===========================================================================
// Pre-split bf16x3 GEMM.  Tile 256x128, 4 waves (2x2), wave 128x64
// (mf=4, nf=2 fragments of 32x32x16).  A: M-rows x K; B: N-rows x K (both
// pre-split hi/lo bf16 row-major).  zmode: 0 none; 1 MoE1-pair (z=expert);
// 2 MoE2-quad (z=(par,kh)); 3 proj split-K2 (z=kh).
// Staging: coalesced (4 lanes = 64B of one row) + register prefetch of the
// next K-tile issued after the barrier (overlaps MFMA).
// ===========================================================================
template<bool WF32, bool WSPLIT>
__global__ __launch_bounds__(256, 2)
void psgemm_kernel(const u16* __restrict__ Ah, const u16* __restrict__ Al, int lda,
                   const u16* __restrict__ Bh, const u16* __restrict__ Bl, int ldb,
                   int K,
                   float* __restrict__ Cf, u16* __restrict__ Ch, u16* __restrict__ Cl,
                   int ldc,
                   const float* __restrict__ bias, const float* __restrict__ residual,
                   const float* __restrict__ row_scale, int rs_stride,
                   int do_relu, int do_accum,
                   int zmode, long sAZ, long sBZ, long sCZ, int sbias)
{
  const int z = blockIdx.z;
  if (zmode == 1) {
    Bh += (size_t)z * sBZ; Bl += (size_t)z * sBZ;
    if (bias) bias += (size_t)z * sbias;
    Ch += (size_t)z * sCZ; Cl += (size_t)z * sCZ;
  } else if (zmode == 2) {
    const int par = z >> 1, kh = z & 1;
    Ah += (size_t)par * sAZ + kh * 2048; Al += (size_t)par * sAZ + kh * 2048;
    Bh += (size_t)par * sBZ + kh * 2048; Bl += (size_t)par * sBZ + kh * 2048;
    Cf += (size_t)z * sCZ;
    row_scale += par;
    if (kh) bias += (size_t)par * sbias; else bias = nullptr;
  } else if (zmode == 3) {
    Ah += z * 512; Al += z * 512; Bh += z * 512; Bl += z * 512;
    Cf += (size_t)z * sCZ;
    if (!z) { bias = nullptr; residual = nullptr; }
  }

  __shared__ __align__(16) u16 As[2][4][256][8];   // 32 KB
  __shared__ __align__(16) u16 Bs[2][4][128][8];   // 16 KB
  const int t = threadIdx.x;
  const int m0 = blockIdx.y * 256, n0 = blockIdx.x * 128;
  const int wid = t >> 6, lane = t & 63;
  const int wr = wid >> 1, wc = wid & 1;
  const int l31 = lane & 31, lhi = lane >> 5;

  f32x16 acc[4][2];
#pragma unroll
  for (int i = 0; i < 4; ++i)
#pragma unroll
    for (int j = 0; j < 2; ++j)
#pragma unroll
      for (int r = 0; r < 16; ++r) acc[i][j][r] = 0.f;

  // staging map: 4 consecutive lanes cover one row's 64B (coalesced)
  const int srow = t >> 2, sc = t & 3;
  const u16* pAh = Ah + (size_t)(m0 + srow) * lda + sc * 8;
  const u16* pAl = Al + (size_t)(m0 + srow) * lda + sc * 8;
  const u16* pBh = Bh + (size_t)(n0 + srow) * ldb + sc * 8;
  const u16* pBl = Bl + (size_t)(n0 + srow) * ldb + sc * 8;

  us8 ra_h[4], ra_l[4], rb_h[2], rb_l[2];
#define LOADT(k0_)                                                        \
  {                                                                       \
    _Pragma("unroll")                                                     \
    for (int i = 0; i < 4; ++i) {                                         \
      ra_h[i] = *(const us8*)&pAh[(size_t)(i * 64) * lda + (k0_)];        \
      ra_l[i] = *(const us8*)&pAl[(size_t)(i * 64) * lda + (k0_)];        \
    }                                                                     \
    _Pragma("unroll")                                                     \
    for (int i = 0; i < 2; ++i) {                                         \
      rb_h[i] = *(const us8*)&pBh[(size_t)(i * 64) * ldb + (k0_)];        \
      rb_l[i] = *(const us8*)&pBl[(size_t)(i * 64) * ldb + (k0_)];        \
    }                                                                     \
  }

  LOADT(0);
  for (int k0 = 0; k0 < K; k0 += 32) {
    __syncthreads();   // previous tile's reads done
#pragma unroll
    for (int i = 0; i < 4; ++i) {
      *(us8*)&As[0][sc][srow + i * 64][0] = ra_h[i];
      *(us8*)&As[1][sc][srow + i * 64][0] = ra_l[i];
    }
#pragma unroll
    for (int i = 0; i < 2; ++i) {
      *(us8*)&Bs[0][sc][srow + i * 64][0] = rb_h[i];
      *(us8*)&Bs[1][sc][srow + i * 64][0] = rb_l[i];
    }
    __syncthreads();
    if (k0 + 32 < K) LOADT(k0 + 32);   // prefetch overlaps MFMA below

#pragma unroll
    for (int ks = 0; ks < 2; ++ks) {
      const int kg = ks * 2 + lhi;
      bf16x8 bh[2], bl[2];
#pragma unroll
      for (int nf = 0; nf < 2; ++nf) {
        bh[nf] = ld_frag(&Bs[0][kg][wc * 64 + nf * 32 + l31][0]);
        bl[nf] = ld_frag(&Bs[1][kg][wc * 64 + nf * 32 + l31][0]);
      }
#pragma unroll
      for (int mf = 0; mf < 4; ++mf) {
        const bf16x8 ah = ld_frag(&As[0][kg][wr * 128 + mf * 32 + l31][0]);
        const bf16x8 al = ld_frag(&As[1][kg][wr * 128 + mf * 32 + l31][0]);
#pragma unroll
        for (int nf = 0; nf < 2; ++nf) {
          acc[mf][nf] = mfma32(al, bh[nf], acc[mf][nf]);
          acc[mf][nf] = mfma32(ah, bl[nf], acc[mf][nf]);
          acc[mf][nf] = mfma32(ah, bh[nf], acc[mf][nf]);
        }
      }
    }
  }
#undef LOADT

  // epilogue: C/D layout col=lane&31, row=(r&3)+8*(r>>2)+4*lhi  (verified)
#pragma unroll
  for (int mf = 0; mf < 4; ++mf)
#pragma unroll
    for (int nf = 0; nf < 2; ++nf) {
      const int col = n0 + wc * 64 + nf * 32 + l31;
      const float bia = bias ? bias[col] : 0.f;
#pragma unroll
      for (int r = 0; r < 16; ++r) {
        const int row = m0 + wr * 128 + mf * 32 + (r & 3) + 8 * (r >> 2) + 4 * lhi;
        float v = acc[mf][nf][r] + bia;
        if (do_relu) v = fmaxf(v, 0.f);
        if (row_scale) v *= row_scale[(size_t)row * rs_stride];
        if (residual) v += residual[(size_t)row * ldc + col];
        if (WF32) {
          float* cp = &Cf[(size_t)row * ldc + col];
          float vv = v;
          if (do_accum) vv += *cp;
          *cp = vv;
        }
        if (WSPLIT) {
          u16 h, l; split2(v, h, l);
          Ch[(size_t)row * ldc + col] = h;
          Cl[(size_t)row * ldc + col] = l;
        }
      }
    }
}

// ---------------------------------------------------------------------------
// Conversion kernels
// ---------------------------------------------------------------------------
__global__ __launch_bounds__(256)
void split_rows_kernel(const float* __restrict__ in, u16* __restrict__ oh,
                       u16* __restrict__ ol, long n4)
{
  const long g = (long)blockIdx.x * 256 + threadIdx.x;
  if (g >= n4) return;
  const float4 v = *(const float4*)&in[g * 4];
  union { u16 s[4]; u64 v64; } ph, pl;
  split2(v.x, ph.s[0], pl.s[0]); split2(v.y, ph.s[1], pl.s[1]);
  split2(v.z, ph.s[2], pl.s[2]); split2(v.w, ph.s[3], pl.s[3]);
  *(u64*)&oh[g * 4] = ph.v64;
  *(u64*)&ol[g * 4] = pl.v64;
}

// transpose + split: in (R,C) fp32 row-major -> out (C,R) hi/lo bf16.
__global__ __launch_bounds__(256)
void split_T_kernel(const float* __restrict__ in, u16* __restrict__ oh,
                    u16* __restrict__ ol, int R, int C)
{
  __shared__ float tile[32][33];
  const size_t zo = (size_t)blockIdx.z * R * C;
  in += zo; oh += zo; ol += zo;
  const int tx = threadIdx.x, ty = threadIdx.y;
  const int r0 = blockIdx.y * 32, c0 = blockIdx.x * 32;
#pragma unroll
  for (int i = 0; i < 4; ++i)
    tile[ty + i * 8][tx] = in[(size_t)(r0 + ty + i * 8) * C + c0 + tx];
  __syncthreads();
#pragma unroll
  for (int i = 0; i < 4; ++i) {
    const float v = tile[tx][ty + i * 8];
    u16 h, l; split2(v, h, l);
    const size_t o = (size_t)(c0 + ty + i * 8) * R + r0 + tx;
    oh[o] = h; ol[o] = l;
  }
}

// im2col + split: col[m][tt*1024+i] = x[b, s+tt-1, i]
__global__ __launch_bounds__(256)
void im2cs_kernel(const float* __restrict__ x, u16* __restrict__ oh,
                  u16* __restrict__ ol)
{
  const long g = (long)blockIdx.x * 256 + threadIdx.x;
  if (g >= (long)MTOT * 3072 / 4) return;
  const long id4 = g * 4;
  const int j = (int)(id4 % 3072);
  const int m = (int)(id4 / 3072);
  const int tt = j >> 10, i = j & 1023;
  const int b = m >> 11, s = m & 2047;
  const int sr = s + tt - 1;
  float4 v = make_float4(0.f, 0.f, 0.f, 0.f);
  if (sr >= 0 && sr < SEQ) v = *(const float4*)&x[((size_t)(b * SEQ + sr) << 10) + i];
  union { u16 s[4]; u64 v64; } ph, pl;
  split2(v.x, ph.s[0], pl.s[0]); split2(v.y, ph.s[1], pl.s[1]);
  split2(v.z, ph.s[2], pl.s[2]); split2(v.w, ph.s[3], pl.s[3]);
  *(u64*)&oh[id4] = ph.v64;
  *(u64*)&ol[id4] = pl.v64;
}

// conv weight pack + split: out[o][tt*1024+i] = cw[o][i][tt]
__global__ __launch_bounds__(256)
void wpks_kernel(const float* __restrict__ cw, u16* __restrict__ oh,
                 u16* __restrict__ ol)
{
  const long g = (long)blockIdx.x * 256 + threadIdx.x;
  if (g >= (long)1024 * 3072 / 4) return;
  const long id4 = g * 4;
  const int o = (int)(id4 / 3072);
  const int kp = (int)(id4 % 3072);
  const int tt = kp >> 10, i = kp & 1023;
  union { u16 s[4]; u64 v64; } ph, pl;
#pragma unroll
  for (int q = 0; q < 4; ++q) {
    const float v = cw[(size_t)o * 3072 + (i + q) * 3 + tt];
    split2(v, ph.s[q], pl.s[q]);
  }
  *(u64*)&oh[id4] = ph.v64;
  *(u64*)&ol[id4] = pl.v64;
}

// ===========================================================================
// MFMA flash attention (swapped QK^T).  grid (16, H, B), block 256 = 4 waves.
// Block: 128 q-rows (32/wave); KV tiles of 64.  Q split-bf16 in regs;
// K split + V^T split staged in XOR-swizzled LDS.  S^T = mfma(K, Q) puts a
// full score row in each lane (q = lane&31) -> in-lane softmax + 1 shfl_xor.
// P -> PV A-frags via v_cvt_pk_bf16_f32 + v_permlane32_swap_b32 (no LDS).
// ===========================================================================
__global__ __launch_bounds__(256)
void attn_mfma_kernel(const float* __restrict__ qkv,
                      u16* __restrict__ ctxh, u16* __restrict__ ctxl)
{
  const int qt = blockIdx.x, h = blockIdx.y, b = blockIdx.z;
  const int t = threadIdx.x;
  const int w = t >> 6, lane = t & 63;
  const int l31 = lane & 31, half = lane >> 5;

  __shared__ __align__(16) u16 Ksh[64 * 64], Ksl[64 * 64];
  __shared__ __align__(16) u16 Vth[64 * 64], Vtl[64 * 64];

  const size_t base = (size_t)b * SEQ * 3072;
  const int hoff = h * 64;
  const int q0 = qt * 128 + w * 32;

  // ---- Q fragments (hi/lo), one q-row per lane ----
  bf16x8 qh[4], ql[4];
  {
    const float* qrow = &qkv[base + (size_t)(q0 + l31) * 3072 + hoff];
#pragma unroll
    for (int ks = 0; ks < 4; ++ks) {
      float v[8];
      *(float4*)&v[0] = *(const float4*)&qrow[ks * 16 + half * 8];
      *(float4*)&v[4] = *(const float4*)&qrow[ks * 16 + half * 8 + 4];
      union { u16 s[8]; us8 v8; } H, L;
#pragma unroll
      for (int j = 0; j < 8; ++j) split2(v[j], H.s[j], L.s[j]);
      qh[ks] = __builtin_bit_cast(bf16x8, H.v8);
      ql[ks] = __builtin_bit_cast(bf16x8, L.v8);
    }
  }

  f32x16 cf[2];
#pragma unroll
  for (int nf = 0; nf < 2; ++nf)
#pragma unroll
    for (int r = 0; r < 16; ++r) cf[nf][r] = 0.f;
  float m_run = -1e30f, l_run = 0.f;

  // staging maps
  const int kkey = t >> 2, kc = t & 3;       // K: 4 lanes per key row
  const int vd = t & 63, vkg = t >> 6;       // V: lane = d column, 16 keys each

  for (int kt = 0; kt < SEQ / 64; ++kt) {
    __syncthreads();   // previous tile's LDS reads done
    // ---- stage K (row-major, swizzled) ----
    {
      const float* kr = &qkv[base + (size_t)(kt * 64 + kkey) * 3072 + 1024 + hoff];
      const int swz = (kkey & 7) << 4;
#pragma unroll
      for (int i = 0; i < 4; ++i) {
        const float4 v = *(const float4*)&kr[kc * 4 + 16 * i];
        union { u16 s[4]; u64 v64; } H, L;
        split2(v.x, H.s[0], L.s[0]); split2(v.y, H.s[1], L.s[1]);
        split2(v.z, H.s[2], L.s[2]); split2(v.w, H.s[3], L.s[3]);
        const int off = (kc * 8 + 32 * i) ^ swz;
        *(u64*)((char*)Ksh + kkey * 128 + off) = H.v64;
        *(u64*)((char*)Ksl + kkey * 128 + off) = L.v64;
      }
    }
    // ---- stage V transposed (Vt[d][key], swizzled) ----
    {
      const float* vc = &qkv[base + (size_t)(kt * 64 + vkg * 16) * 3072 + 2048 + hoff + vd];
      union { u16 s[8]; us8 v8; } H0, L0, H1, L1;
#pragma unroll
      for (int i = 0; i < 8; ++i) {
        split2(vc[(size_t)i * 3072], H0.s[i], L0.s[i]);
        split2(vc[(size_t)(i + 8) * 3072], H1.s[i], L1.s[i]);
      }
      const int swz = (vd & 7) << 4;
      const int off0 = (vkg * 32) ^ swz, off1 = (vkg * 32 + 16) ^ swz;
      *(us8*)((char*)Vth + vd * 128 + off0) = H0.v8;
      *(us8*)((char*)Vth + vd * 128 + off1) = H1.v8;
      *(us8*)((char*)Vtl + vd * 128 + off0) = L0.v8;
      *(us8*)((char*)Vtl + vd * 128 + off1) = L1.v8;
    }
    __syncthreads();

    // ---- S^T = K . Q^T  (3-term split) ----
    f32x16 sf[2];
#pragma unroll
    for (int f = 0; f < 2; ++f)
#pragma unroll
      for (int r = 0; r < 16; ++r) sf[f][r] = 0.f;
#pragma unroll
    for (int ks = 0; ks < 4; ++ks) {
      const int rb = (ks * 32 + half * 16);
#pragma unroll
      for (int f = 0; f < 2; ++f) {
        const int key = f * 32 + l31;
        const int off = rb ^ ((key & 7) << 4);
        const bf16x8 kh = __builtin_bit_cast(bf16x8, *(const us8*)((char*)Ksh + key * 128 + off));
        const bf16x8 kl = __builtin_bit_cast(bf16x8, *(const us8*)((char*)Ksl + key * 128 + off));
        sf[f] = mfma32(kl, qh[ks], sf[f]);
        sf[f] = mfma32(kh, ql[ks], sf[f]);
        sf[f] = mfma32(kh, qh[ks], sf[f]);
      }
    }

    // ---- online softmax (per-lane row; scale 0.125) ----
    float tmax = -1e30f;
#pragma unroll
    for (int f = 0; f < 2; ++f)
#pragma unroll
      for (int r = 0; r < 16; ++r) tmax = fmaxf(tmax, sf[f][r]);
    tmax *= 0.125f;
    tmax = fmaxf(tmax, __shfl_xor(tmax, 32, 64));
    const float m_new = fmaxf(m_run, tmax);
    const float resc = __expf(m_run - m_new);
    float lt = 0.f;
#pragma unroll
    for (int f = 0; f < 2; ++f)
#pragma unroll
      for (int r = 0; r < 16; ++r) {
        const float p = __expf(__builtin_fmaf(sf[f][r], 0.125f, -m_new));
        sf[f][r] = p; lt += p;
      }
    lt += __shfl_xor(lt, 32, 64);
    l_run = l_run * resc + lt;
    m_run = m_new;
    // rescale ctx: resc belongs to q = lane&31; ctx reg r belongs to q(r)
#pragma unroll
    for (int r = 0; r < 16; ++r) {
      const int qr = (r & 3) + 8 * (r >> 2) + 4 * half;
      const float rs = __shfl(resc, qr, 64);
      cf[0][r] *= rs; cf[1][r] *= rs;
    }

    // ---- P -> A-fragments: cvt_pk pairs + permlane32_swap ----
    u32 W0[2][4], W1[2][4];
#pragma unroll
    for (int f = 0; f < 2; ++f)
#pragma unroll
      for (int g = 0; g < 4; ++g) {
        u32 w0, w1;
        asm("v_cvt_pk_bf16_f32 %0, %1, %2" : "=v"(w0) : "v"(sf[f][4 * g]), "v"(sf[f][4 * g + 1]));
        asm("v_cvt_pk_bf16_f32 %0, %1, %2" : "=v"(w1) : "v"(sf[f][4 * g + 2]), "v"(sf[f][4 * g + 3]));
        W0[f][g] = w0; W1[f][g] = w1;
      }
    bf16x8 PA[4];
#pragma unroll
    for (int ks = 0; ks < 4; ++ks) {
      const int f = ks >> 1, g0 = (ks & 1) * 2;
      u32 a = W0[f][g0], b2 = W0[f][g0 + 1];
      u32 c = W1[f][g0], d2 = W1[f][g0 + 1];
      asm volatile("v_permlane32_swap_b32 %0, %1" : "+v"(a), "+v"(b2));
      asm volatile("v_permlane32_swap_b32 %0, %1" : "+v"(c), "+v"(d2));
      union { u32 w[4]; us8 v8; } pa;
      pa.w[0] = a; pa.w[1] = c; pa.w[2] = b2; pa.w[3] = d2;
      PA[ks] = __builtin_bit_cast(bf16x8, pa.v8);
    }

    // ---- ctx += P . V  (V split) ----
#pragma unroll
    for (int ks = 0; ks < 4; ++ks) {
      const int rb = (ks * 32 + half * 16);
#pragma unroll
      for (int nf = 0; nf < 2; ++nf) {
        const int dd = nf * 32 + l31;
        const int off = rb ^ ((dd & 7) << 4);
        const bf16x8 vh = __builtin_bit_cast(bf16x8, *(const us8*)((char*)Vth + dd * 128 + off));
        const bf16x8 vl = __builtin_bit_cast(bf16x8, *(const us8*)((char*)Vtl + dd * 128 + off));
        cf[nf] = mfma32(PA[ks], vh, cf[nf]);
        cf[nf] = mfma32(PA[ks], vl, cf[nf]);
      }
    }
  }

  // ---- finalize: ctx /= l, write split-bf16 ----
  const float invl = 1.f / l_run;
#pragma unroll
  for (int r = 0; r < 16; ++r) {
    const int qr = (r & 3) + 8 * (r >> 2) + 4 * half;
    const float il = __shfl(invl, qr, 64);
    const size_t row = (size_t)(b * SEQ + q0 + qr) * 1024 + hoff;
#pragma unroll
    for (int nf = 0; nf < 2; ++nf) {
      const float v = cf[nf][r] * il;
      u16 hh, ll; split2(v, hh, ll);
      ctxh[row + nf * 32 + l31] = hh;
      ctxl[row + nf * 32 + l31] = ll;
    }
  }
}

// ---------------------------------------------------------------------------
// LayerNorm: out = LN(in + r1 + r2 + r3 + r4) * g + b; optional split-out.
// ---------------------------------------------------------------------------
__global__ __launch_bounds__(256)
void ln_kernel(const float* __restrict__ in, const float* __restrict__ r1,
               const float* __restrict__ r2, const float* __restrict__ r3,
               const float* __restrict__ r4,
               const float* __restrict__ g, const float* __restrict__ bt,
               float* __restrict__ outf, u16* __restrict__ outh, u16* __restrict__ outl)
{
  const int row = blockIdx.x, t = threadIdx.x;
  const size_t off = ((size_t)row << 10) + t * 4;
  float4 v = *(const float4*)&in[off];
  if (r1) { const float4 r = *(const float4*)&r1[off]; v.x += r.x; v.y += r.y; v.z += r.z; v.w += r.w; }
  if (r2) { const float4 r = *(const float4*)&r2[off]; v.x += r.x; v.y += r.y; v.z += r.z; v.w += r.w; }
  if (r3) { const float4 r = *(const float4*)&r3[off]; v.x += r.x; v.y += r.y; v.z += r.z; v.w += r.w; }
  if (r4) { const float4 r = *(const float4*)&r4[off]; v.x += r.x; v.y += r.y; v.z += r.z; v.w += r.w; }
  float s  = v.x + v.y + v.z + v.w;
  float ss = v.x * v.x + v.y * v.y + v.z * v.z + v.w * v.w;
#pragma unroll
  for (int o = 32; o; o >>= 1) {
    s  += __shfl_xor(s, o, 64);
    ss += __shfl_xor(ss, o, 64);
  }
  __shared__ float red[8];
  if ((t & 63) == 0) { red[(t >> 6) * 2] = s; red[(t >> 6) * 2 + 1] = ss; }
  __syncthreads();
  s  = red[0] + red[2] + red[4] + red[6];
  ss = red[1] + red[3] + red[5] + red[7];
  const float mu   = s * (1.f / 1024.f);
  const float var  = ss * (1.f / 1024.f) - mu * mu;
  const float rstd = rsqrtf(var + 1e-5f);
  const float4 gg = *(const float4*)&g[t * 4];
  const float4 bb = *(const float4*)&bt[t * 4];
  float4 o;
  o.x = (v.x - mu) * rstd * gg.x + bb.x;
  o.y = (v.y - mu) * rstd * gg.y + bb.y;
  o.z = (v.z - mu) * rstd * gg.z + bb.z;
  o.w = (v.w - mu) * rstd * gg.w + bb.w;
  if (outf) *(float4*)&outf[off] = o;
  if (outh) {
    union { u16 s[4]; u64 v64; } ph, pl;
    split2(o.x, ph.s[0], pl.s[0]); split2(o.y, ph.s[1], pl.s[1]);
    split2(o.z, ph.s[2], pl.s[2]); split2(o.w, ph.s[3], pl.s[3]);
    *(u64*)&outh[off] = ph.v64;
    *(u64*)&outl[off] = pl.v64;
  }
}

// ---------------------------------------------------------------------------
// MoE gate: probs[m, 0..7] = softmax(x[m,:] @ gate_w + gate_b). 1 wave / row.
// ---------------------------------------------------------------------------
__global__ __launch_bounds__(64)
void gate_kernel(const float* __restrict__ x, const float* __restrict__ gw,
                 const float* __restrict__ gb, float* __restrict__ probs)
{
  const int m = blockIdx.x, lane = threadIdx.x;
  float acc[8];
#pragma unroll
  for (int e = 0; e < 8; ++e) acc[e] = 0.f;
  for (int k = lane; k < 1024; k += 64) {
    const float xv = x[((size_t)m << 10) + k];
    const float4 g0 = *(const float4*)&gw[k * 8];
    const float4 g1 = *(const float4*)&gw[k * 8 + 4];
    acc[0] = __builtin_fmaf(xv, g0.x, acc[0]);
    acc[1] = __builtin_fmaf(xv, g0.y, acc[1]);
    acc[2] = __builtin_fmaf(xv, g0.z, acc[2]);
    acc[3] = __builtin_fmaf(xv, g0.w, acc[3]);
    acc[4] = __builtin_fmaf(xv, g1.x, acc[4]);
    acc[5] = __builtin_fmaf(xv, g1.y, acc[5]);
    acc[6] = __builtin_fmaf(xv, g1.z, acc[6]);
    acc[7] = __builtin_fmaf(xv, g1.w, acc[7]);
  }
#pragma unroll
  for (int o = 32; o; o >>= 1)
#pragma unroll
    for (int e = 0; e < 8; ++e) acc[e] += __shfl_xor(acc[e], o, 64);
  float lg[8], mx = -1e30f;
#pragma unroll
  for (int e = 0; e < 8; ++e) { lg[e] = acc[e] + gb[e]; mx = fmaxf(mx, lg[e]); }
  float se = 0.f;
#pragma unroll
  for (int e = 0; e < 8; ++e) { lg[e] = __expf(lg[e] - mx); se += lg[e]; }
  const float inv = 1.f / se;
  if (lane < 8) probs[(size_t)m * 8 + lane] = lg[lane] * inv;
}

// ---------------------------------------------------------------------------
extern "C" void kernel_launch(void* const* d_in, const int* in_sizes, int n_in,
                              void* d_out, int out_size, void* d_ws, size_t ws_size,
                              hipStream_t stream)
{
  const float* x      = (const float*)d_in[0];
  const float* conv_w = (const float*)d_in[1];
  const float* conv_b = (const float*)d_in[2];
  const float* wqkv   = (const float*)d_in[3];
  const float* bqkv   = (const float*)d_in[4];
  const float* wo     = (const float*)d_in[5];
  const float* bo     = (const float*)d_in[6];
  const float* ln1_g  = (const float*)d_in[7];
  const float* ln1_b  = (const float*)d_in[8];
  const float* gate_w = (const float*)d_in[9];
  const float* gate_b = (const float*)d_in[10];
  const float* w1     = (const float*)d_in[11];
  const float* b1     = (const float*)d_in[12];
  const float* w2     = (const float*)d_in[13];
  const float* b2     = (const float*)d_in[14];
  const float* ln2_g  = (const float*)d_in[15];
  const float* ln2_b  = (const float*)d_in[16];
  float* out = (float*)d_out;

  const dim3 blk256(256);
  char* W = (char*)d_ws;
#define MB(x) ((size_t)(x) << 20)
  // ws layout (proven in round 4; ws_size >= 481 MiB confirmed by round 4 run)
  float* x1_f   = (float*)(W + MB(0));     // 16 MiB
  float* moe_f  = (float*)(W + MB(16));    // 4 x 16 MiB
  float* probs  = (float*)(W + MB(80));
  u16* x1s_h    = (u16*)(W + MB(81));
  u16* x1s_l    = (u16*)(W + MB(89));
  u16* hbs_h    = (u16*)(W + MB(97));      // MoE hidden (pair-z stride 33554432)
  u16* hbs_l    = (u16*)(W + MB(129));
  u16* im2cs_h  = (u16*)(W + MB(97));      // early tenant of hbs slot
  u16* im2cs_l  = (u16*)(W + MB(121));
  u16* wpks_h   = (u16*)(W + MB(145));
  u16* wpks_l   = (u16*)(W + MB(151));
  u16* ctxs_h   = (u16*)(W + MB(157));
  u16* ctxs_l   = (u16*)(W + MB(165));
  u16* wos_h    = (u16*)(W + MB(173));
  u16* wos_l    = (u16*)(W + MB(175));
  float* res1a  = (float*)(W + MB(177));
  float* res1b  = (float*)(W + MB(193));
  u16* w1s_h    = (u16*)(W + MB(225));
  u16* w1s_l    = (u16*)(W + MB(289));
  float* qkv_f  = (float*)(W + MB(225));   // early tenant of w1s slot
  float* yconv_f= (float*)(W + MB(273));
  u16* yconvs_h = (u16*)(W + MB(289));
  u16* yconvs_l = (u16*)(W + MB(297));
  u16* w2s_h    = (u16*)(W + MB(353));
  u16* w2s_l    = (u16*)(W + MB(417));
  u16* wqkvs_h  = (u16*)(W + MB(353));     // early tenant of w2s slot
  u16* wqkvs_l  = (u16*)(W + MB(359));

  // 1) conv staging (split) + conv GEMM -> yconv (f32 + split)
  im2cs_kernel<<<dim3(12288), blk256, 0, stream>>>(x, im2cs_h, im2cs_l);
  wpks_kernel<<<dim3(3072), blk256, 0, stream>>>(conv_w, wpks_h, wpks_l);
  psgemm_kernel<true, true><<<dim3(8, 16, 1), blk256, 0, stream>>>(
      im2cs_h, im2cs_l, 3072, wpks_h, wpks_l, 3072, 3072,
      yconv_f, yconvs_h, yconvs_l, 1024,
      conv_b, nullptr, nullptr, 0, 0, 0, 0, 0, 0, 0, 0);

  // 2) QKV projection (fp32 out for attention)
  split_rows_kernel<<<dim3(3072), blk256, 0, stream>>>(wqkv, wqkvs_h, wqkvs_l, 786432);
  psgemm_kernel<true, false><<<dim3(24, 16, 1), blk256, 0, stream>>>(
      yconvs_h, yconvs_l, 1024, wqkvs_h, wqkvs_l, 1024, 1024,
      qkv_f, nullptr, nullptr, 3072,
      bqkv, nullptr, nullptr, 0, 0, 0, 0, 0, 0, 0, 0);

  // 3) w2 convert (after qkv GEMM; overwrites wqkvs)
  split_T_kernel<<<dim3(32, 128, 8), dim3(32, 8), 0, stream>>>(w2, w2s_h, w2s_l, 4096, 1024);

  // 4) MFMA flash attention -> ctx split
  attn_mfma_kernel<<<dim3(SEQ / 128, NHEAD, NBAT), blk256, 0, stream>>>(
      qkv_f, ctxs_h, ctxs_l);

  // 5) out projection split-K2 -> res1a/res1b (bias+residual on slice 1)
  split_rows_kernel<<<dim3(1024), blk256, 0, stream>>>(wo, wos_h, wos_l, 262144);
  psgemm_kernel<true, false><<<dim3(8, 16, 2), blk256, 0, stream>>>(
      ctxs_h, ctxs_l, 1024, wos_h, wos_l, 1024, 512,
      res1a, nullptr, nullptr, 1024,
      bo, yconv_f, nullptr, 0, 0, 0, 3, 0, 0, 4194304, 0);

  // 6) w1 convert (after proj; overwrites qkv/yconv)
  split_T_kernel<<<dim3(128, 32, 8), dim3(32, 8), 0, stream>>>(w1, w1s_h, w1s_l, 1024, 4096);

  // 7) LN1 -> x1 (f32 + split)
  ln_kernel<<<dim3(MTOT), blk256, 0, stream>>>(
      res1a, res1b, nullptr, nullptr, nullptr, ln1_g, ln1_b, x1_f, x1s_h, x1s_l);

  // 8) gate
  gate_kernel<<<dim3(MTOT), dim3(64), 0, stream>>>(x1_f, gate_w, gate_b, probs);

  // 9) MoE: expert pairs; MoE1 pair -> hbs split; MoE2 quad -> moe[0..3]
  for (int p = 0; p < 4; ++p) {
    const int e0 = 2 * p;
    psgemm_kernel<false, true><<<dim3(32, 16, 2), blk256, 0, stream>>>(
        x1s_h, x1s_l, 1024,
        w1s_h + (size_t)e0 * 4194304, w1s_l + (size_t)e0 * 4194304, 1024, 1024,
        nullptr, hbs_h, hbs_l, 4096,
        b1 + (size_t)e0 * 4096, nullptr, nullptr, 0, 1 /*relu*/, 0,
        1, 0, 4194304, 33554432, 4096);
    psgemm_kernel<true, false><<<dim3(8, 16, 4), blk256, 0, stream>>>(
        hbs_h, hbs_l, 4096,
        w2s_h + (size_t)e0 * 4194304, w2s_l + (size_t)e0 * 4194304, 4096, 2048,
        moe_f, nullptr, nullptr, 1024,
        b2 + (size_t)e0 * 1024, nullptr, probs + e0, 8, 0, (p > 0),
        2, 33554432, 4194304, 4194304, 1024);
  }

  // 10) LN2(x1 + moe0..3) -> out
  ln_kernel<<<dim3(MTOT), blk256, 0, stream>>>(
      x1_f, moe_f, moe_f + 4194304, moe_f + 8388608, moe_f + 12582912,
      ln2_g, ln2_b, out, nullptr, nullptr);
#undef MB
}

// Round 7
// 1781.029 us; speedup vs baseline: 2.2740x; 1.6600x over previous
//
#include <hip/hip_runtime.h>

// Problem constants
#define SEQ   2048
#define NBAT  2
#define MTOT  4096        // NBAT*SEQ
#define DIMC  1024
#define DFFC  4096
#define NEXP  8
#define NHEAD 16

typedef unsigned short u16;
typedef unsigned int   u32;
typedef unsigned long long u64;
typedef __attribute__((ext_vector_type(8)))  _Float16       f16x8;
typedef __attribute__((ext_vector_type(8)))  unsigned short us8;
typedef __attribute__((ext_vector_type(4)))  float          f32x4;
typedef __attribute__((ext_vector_type(16))) float          f32x16;

__device__ __forceinline__ u16 cvt16(float a) {
  return __builtin_bit_cast(u16, (_Float16)a);
}
__device__ __forceinline__ f16x8 ld_f16(const u16* p) {
  return __builtin_bit_cast(f16x8, *(const us8*)p);
}
__device__ __forceinline__ f32x4 mfma16(f16x8 a, f16x8 b, f32x4 c) {
  return __builtin_amdgcn_mfma_f32_16x16x32_f16(a, b, c, 0, 0, 0);
}
__device__ __forceinline__ f32x16 mfma32f(f16x8 a, f16x8 b, f32x16 c) {
  return __builtin_amdgcn_mfma_f32_32x32x16_f16(a, b, c, 0, 0, 0);
}
// async global->LDS, 16B per lane: dst = uniform base + lane*16
__device__ __forceinline__ void gload16(const u16* g, u16* l) {
  __builtin_amdgcn_global_load_lds(
      (const __attribute__((address_space(1))) void*)g,
      (__attribute__((address_space(3))) void*)l, 16, 0, 0);
}

// ===========================================================================
// fp16-single MFMA GEMM, m97 structure: 128x128 tile, 4 waves (2x2), wave
// 64x64 = 4x4 frags of 16x16x32_f16.  A: M-rows x K fp16; B: N-rows x K fp16.
// global_load_lds staging into linear LDS [kg][row][8] (conflict-free).
// XCD-aware bijective block swizzle (requires nwg%8==0 -- true all call sites).
// zmode: 0 none; 1 MoE1 (z: B,C16,bias); 2 MoE2 (z: A,B,Cf,bias,row_scale);
//        3 split-K2 (z: A/B k-offset, Cf; bias/residual only z==1).
// ===========================================================================
template<bool WF32, bool WF16>
__global__ __launch_bounds__(256)
void pgemm16_kernel(const u16* __restrict__ A16, int lda,
                    const u16* __restrict__ B16, int ldb, int K,
                    float* __restrict__ Cf, u16* __restrict__ Ch, int ldc,
                    const float* __restrict__ bias,
                    const float* __restrict__ residual,
                    const float* __restrict__ row_scale, int rs_stride,
                    int do_relu, int do_accum,
                    int zmode, long sAZ, long sBZ, long sCZ, int sbias)
{
  const int z = blockIdx.z;
  if (zmode == 1) {
    B16 += (size_t)z * sBZ;
    Ch  += (size_t)z * sCZ;
    bias += (size_t)z * sbias;
  } else if (zmode == 2) {
    A16 += (size_t)z * sAZ;
    B16 += (size_t)z * sBZ;
    Cf  += (size_t)z * sCZ;
    bias += (size_t)z * sbias;
    row_scale += z;
  } else if (zmode == 3) {
    A16 += (size_t)z * sAZ;  B16 += (size_t)z * sAZ;   // k-offset
    Cf  += (size_t)z * sCZ;
    if (!z) { bias = nullptr; residual = nullptr; }
  }

  // XCD-aware swizzle (bijective since nwg % 8 == 0)
  const int gx = gridDim.x;
  int bid = blockIdx.y * gx + blockIdx.x;
  const int cpx = (gx * gridDim.y) >> 3;
  bid = (bid & 7) * cpx + (bid >> 3);
  const int m0 = (bid / gx) * 128, n0 = (bid % gx) * 128;

  __shared__ __align__(16) u16 As[4][128][8];   // 8 KB  [kg][row][8]
  __shared__ __align__(16) u16 Bs[4][128][8];   // 8 KB
  const int t = threadIdx.x;
  const int wid = t >> 6, lane = t & 63;
  const int wr = wid >> 1, wc = wid & 1;
  const int l15 = lane & 15, l4 = lane >> 4;

  f32x4 acc[4][4];
#pragma unroll
  for (int i = 0; i < 4; ++i)
#pragma unroll
    for (int j = 0; j < 4; ++j)
#pragma unroll
      for (int r = 0; r < 4; ++r) acc[i][j][r] = 0.f;

  // staging slots: instr q = wid*2 + i covers chunks [q*64, q*64+64)
  const int s0  = (wid * 2) * 64 + lane, s1 = s0 + 64;
  const int kg0 = s0 >> 7, r0s = s0 & 127;
  const int kg1 = s1 >> 7, r1s = s1 & 127;
  u16* ldsA0 = (u16*)As + (wid * 2) * 512;
  u16* ldsA1 = (u16*)As + (wid * 2 + 1) * 512;
  u16* ldsB0 = (u16*)Bs + (wid * 2) * 512;
  u16* ldsB1 = (u16*)Bs + (wid * 2 + 1) * 512;
  const u16* gA0 = A16 + (size_t)(m0 + r0s) * lda + kg0 * 8;
  const u16* gA1 = A16 + (size_t)(m0 + r1s) * lda + kg1 * 8;
  const u16* gB0 = B16 + (size_t)(n0 + r0s) * ldb + kg0 * 8;
  const u16* gB1 = B16 + (size_t)(n0 + r1s) * ldb + kg1 * 8;

  for (int k0 = 0; k0 < K; k0 += 32) {
    if (k0) __syncthreads();          // previous compute done -> LDS free
    gload16(gA0 + k0, ldsA0);
    gload16(gA1 + k0, ldsA1);
    gload16(gB0 + k0, ldsB0);
    gload16(gB1 + k0, ldsB1);
    __syncthreads();                  // vmcnt drained -> tile ready

    f16x8 af[4], bf[4];
#pragma unroll
    for (int mf = 0; mf < 4; ++mf) af[mf] = ld_f16(&As[l4][wr * 64 + mf * 16 + l15][0]);
#pragma unroll
    for (int nf = 0; nf < 4; ++nf) bf[nf] = ld_f16(&Bs[l4][wc * 64 + nf * 16 + l15][0]);
#pragma unroll
    for (int mf = 0; mf < 4; ++mf)
#pragma unroll
      for (int nf = 0; nf < 4; ++nf)
        acc[mf][nf] = mfma16(af[mf], bf[nf], acc[mf][nf]);
  }

  // epilogue: 16x16 C/D layout col=lane&15, row=(lane>>4)*4+r (verified)
#pragma unroll
  for (int mf = 0; mf < 4; ++mf)
#pragma unroll
    for (int nf = 0; nf < 4; ++nf) {
      const int col = n0 + wc * 64 + nf * 16 + l15;
      const float bia = bias ? bias[col] : 0.f;
#pragma unroll
      for (int r = 0; r < 4; ++r) {
        const int row = m0 + wr * 64 + mf * 16 + l4 * 4 + r;
        float v = acc[mf][nf][r] + bia;
        if (do_relu)   v = fmaxf(v, 0.f);
        if (row_scale) v *= row_scale[(size_t)row * rs_stride];
        if (residual)  v += residual[(size_t)row * ldc + col];
        if (WF32) {
          float* cp = &Cf[(size_t)row * ldc + col];
          float vv = v;
          if (do_accum) vv += *cp;
          *cp = vv;
        }
        if (WF16) Ch[(size_t)row * ldc + col] = cvt16(v);
      }
    }
}

// ---------------------------------------------------------------------------
// Conversion kernels (fp32 -> fp16 single)
// ---------------------------------------------------------------------------
__global__ __launch_bounds__(256)
void cvt_rows16_kernel(const float* __restrict__ in, u16* __restrict__ o, long n4)
{
  const long g = (long)blockIdx.x * 256 + threadIdx.x;
  if (g >= n4) return;
  const float4 v = *(const float4*)&in[g * 4];
  union { u16 s[4]; u64 v64; } p;
  p.s[0] = cvt16(v.x); p.s[1] = cvt16(v.y); p.s[2] = cvt16(v.z); p.s[3] = cvt16(v.w);
  *(u64*)&o[g * 4] = p.v64;
}

// transpose + convert: in (R,C) fp32 row-major -> out (C,R) fp16
__global__ __launch_bounds__(256)
void cvt_T16_kernel(const float* __restrict__ in, u16* __restrict__ o, int R, int C)
{
  __shared__ float tile[32][33];
  const size_t zo = (size_t)blockIdx.z * R * C;
  in += zo; o += zo;
  const int tx = threadIdx.x, ty = threadIdx.y;
  const int r0 = blockIdx.y * 32, c0 = blockIdx.x * 32;
#pragma unroll
  for (int i = 0; i < 4; ++i)
    tile[ty + i * 8][tx] = in[(size_t)(r0 + ty + i * 8) * C + c0 + tx];
  __syncthreads();
#pragma unroll
  for (int i = 0; i < 4; ++i)
    o[(size_t)(c0 + ty + i * 8) * R + r0 + tx] = cvt16(tile[tx][ty + i * 8]);
}

// im2col + convert: col[m][tt*1024+i] = x[b, s+tt-1, i]
__global__ __launch_bounds__(256)
void im2c16_kernel(const float* __restrict__ x, u16* __restrict__ o)
{
  const long g = (long)blockIdx.x * 256 + threadIdx.x;
  if (g >= (long)MTOT * 3072 / 4) return;
  const long id4 = g * 4;
  const int j = (int)(id4 % 3072);
  const int m = (int)(id4 / 3072);
  const int tt = j >> 10, i = j & 1023;
  const int b = m >> 11, s = m & 2047;
  const int sr = s + tt - 1;
  float4 v = make_float4(0.f, 0.f, 0.f, 0.f);
  if (sr >= 0 && sr < SEQ) v = *(const float4*)&x[((size_t)(b * SEQ + sr) << 10) + i];
  union { u16 s[4]; u64 v64; } p;
  p.s[0] = cvt16(v.x); p.s[1] = cvt16(v.y); p.s[2] = cvt16(v.z); p.s[3] = cvt16(v.w);
  *(u64*)&o[id4] = p.v64;
}

// conv weight pack + convert: out[o][tt*1024+i] = cw[o][i][tt]
__global__ __launch_bounds__(256)
void wpk16_kernel(const float* __restrict__ cw, u16* __restrict__ o)
{
  const long g = (long)blockIdx.x * 256 + threadIdx.x;
  if (g >= (long)1024 * 3072 / 4) return;
  const long id4 = g * 4;
  const int oc = (int)(id4 / 3072);
  const int kp = (int)(id4 % 3072);
  const int tt = kp >> 10, i = kp & 1023;
  union { u16 s[4]; u64 v64; } p;
#pragma unroll
  for (int q = 0; q < 4; ++q)
    p.s[q] = cvt16(cw[(size_t)oc * 3072 + (i + q) * 3 + tt]);
  *(u64*)&o[id4] = p.v64;
}

// ===========================================================================
// fp16 MFMA flash attention (swapped QK^T).  grid (16, H, B), block 256.
// qkv fp16 row-major (M,3072) q|k|v.  Per block 128 q-rows (32/wave).
// K + V^T staged in XOR-swizzled LDS (single fp16 streams).
// S^T = mfma(K, Q): lane owns score row (q = lane&31) -> in-lane softmax.
// P -> PV A-frags via v_cvt_pkrtz_f16_f32 + v_permlane32_swap_b32.
// ===========================================================================
__global__ __launch_bounds__(256)
void attn16_kernel(const u16* __restrict__ qkv, u16* __restrict__ ctx16)
{
  const int qt = blockIdx.x, h = blockIdx.y, b = blockIdx.z;
  const int t = threadIdx.x;
  const int w = t >> 6, lane = t & 63;
  const int l31 = lane & 31, half = lane >> 5;

  __shared__ __align__(16) u16 Ks[64 * 64];   // 8 KB
  __shared__ __align__(16) u16 Vt[64 * 64];   // 8 KB

  const size_t base = (size_t)b * SEQ * 3072;
  const int hoff = h * 64;
  const int q0 = qt * 128 + w * 32;

  // Q frags: lane l31 owns q-row q0+l31; frag ks holds k = ks*16+half*8 ..+8
  f16x8 qh[4];
  {
    const u16* qrow = &qkv[base + (size_t)(q0 + l31) * 3072 + hoff];
#pragma unroll
    for (int ks = 0; ks < 4; ++ks) qh[ks] = ld_f16(&qrow[ks * 16 + half * 8]);
  }

  f32x16 cf[2];
#pragma unroll
  for (int nf = 0; nf < 2; ++nf)
#pragma unroll
    for (int r = 0; r < 16; ++r) cf[nf][r] = 0.f;
  float m_run = -1e30f, l_run = 0.f;

  const int kkey = t >> 2, kc = t & 3;       // K staging: 4 lanes per key row
  const int vd = t & 63, vkg = t >> 6;       // V staging: lane = d column

  for (int kt = 0; kt < SEQ / 64; ++kt) {
    __syncthreads();
    // stage K (row-major fp16, byte ^= (row&7)<<4 swizzle)
    {
      const u16* kr = &qkv[base + (size_t)(kt * 64 + kkey) * 3072 + 1024 + hoff];
      const int swz = (kkey & 7) << 4;
#pragma unroll
      for (int i = 0; i < 2; ++i) {
        const us8 v = *(const us8*)&kr[kc * 16 + i * 8];
        *(us8*)((char*)Ks + kkey * 128 + ((kc * 32 + i * 16) ^ swz)) = v;
      }
    }
    // stage V transposed (Vt[d][key], swizzled)
    {
      const u16* vc = &qkv[base + (size_t)(kt * 64 + vkg * 16) * 3072 + 2048 + hoff + vd];
      union { u16 s[8]; us8 v8; } V0, V1;
#pragma unroll
      for (int i = 0; i < 8; ++i) {
        V0.s[i] = vc[(size_t)i * 3072];
        V1.s[i] = vc[(size_t)(i + 8) * 3072];
      }
      const int swz = (vd & 7) << 4;
      *(us8*)((char*)Vt + vd * 128 + ((vkg * 32) ^ swz))      = V0.v8;
      *(us8*)((char*)Vt + vd * 128 + ((vkg * 32 + 16) ^ swz)) = V1.v8;
    }
    __syncthreads();

    // ---- S^T = K . Q^T (single fp16) ----
    f32x16 sf[2];
#pragma unroll
    for (int f = 0; f < 2; ++f)
#pragma unroll
      for (int r = 0; r < 16; ++r) sf[f][r] = 0.f;
#pragma unroll
    for (int ks = 0; ks < 4; ++ks) {
      const int rb = ks * 32 + half * 16;
#pragma unroll
      for (int f = 0; f < 2; ++f) {
        const int key = f * 32 + l31;
        const int off = rb ^ ((key & 7) << 4);
        const f16x8 kh = __builtin_bit_cast(f16x8, *(const us8*)((char*)Ks + key * 128 + off));
        sf[f] = mfma32f(kh, qh[ks], sf[f]);
      }
    }

    // ---- online softmax (per-lane row; scale 0.125) ----
    float tmax = -1e30f;
#pragma unroll
    for (int f = 0; f < 2; ++f)
#pragma unroll
      for (int r = 0; r < 16; ++r) tmax = fmaxf(tmax, sf[f][r]);
    tmax *= 0.125f;
    tmax = fmaxf(tmax, __shfl_xor(tmax, 32, 64));
    const float m_new = fmaxf(m_run, tmax);
    const float resc = __expf(m_run - m_new);
    float lt = 0.f;
#pragma unroll
    for (int f = 0; f < 2; ++f)
#pragma unroll
      for (int r = 0; r < 16; ++r) {
        const float p = __expf(__builtin_fmaf(sf[f][r], 0.125f, -m_new));
        sf[f][r] = p; lt += p;
      }
    lt += __shfl_xor(lt, 32, 64);
    l_run = l_run * resc + lt;
    m_run = m_new;
#pragma unroll
    for (int r = 0; r < 16; ++r) {
      const int qr = (r & 3) + 8 * (r >> 2) + 4 * half;
      const float rs = __shfl(resc, qr, 64);
      cf[0][r] *= rs; cf[1][r] *= rs;
    }

    // ---- P -> A-frags: cvt_pkrtz pairs + permlane32_swap ----
    u32 W0[2][4], W1[2][4];
#pragma unroll
    for (int f = 0; f < 2; ++f)
#pragma unroll
      for (int g = 0; g < 4; ++g) {
        auto p0 = __builtin_amdgcn_cvt_pkrtz(sf[f][4 * g], sf[f][4 * g + 1]);
        auto p1 = __builtin_amdgcn_cvt_pkrtz(sf[f][4 * g + 2], sf[f][4 * g + 3]);
        W0[f][g] = __builtin_bit_cast(u32, p0);
        W1[f][g] = __builtin_bit_cast(u32, p1);
      }
    f16x8 PA[4];
#pragma unroll
    for (int ks = 0; ks < 4; ++ks) {
      const int f = ks >> 1, g0 = (ks & 1) * 2;
      u32 a = W0[f][g0], b2 = W0[f][g0 + 1];
      u32 c = W1[f][g0], d2 = W1[f][g0 + 1];
      asm volatile("v_permlane32_swap_b32 %0, %1" : "+v"(a), "+v"(b2));
      asm volatile("v_permlane32_swap_b32 %0, %1" : "+v"(c), "+v"(d2));
      union { u32 w[4]; us8 v8; } pa;
      pa.w[0] = a; pa.w[1] = c; pa.w[2] = b2; pa.w[3] = d2;
      PA[ks] = __builtin_bit_cast(f16x8, pa.v8);
    }

    // ---- ctx += P . V ----
#pragma unroll
    for (int ks = 0; ks < 4; ++ks) {
      const int rb = ks * 32 + half * 16;
#pragma unroll
      for (int nf = 0; nf < 2; ++nf) {
        const int dd = nf * 32 + l31;
        const int off = rb ^ ((dd & 7) << 4);
        const f16x8 vh = __builtin_bit_cast(f16x8, *(const us8*)((char*)Vt + dd * 128 + off));
        cf[nf] = mfma32f(PA[ks], vh, cf[nf]);
      }
    }
  }

  // ---- finalize ----
  const float invl = 1.f / l_run;
#pragma unroll
  for (int r = 0; r < 16; ++r) {
    const int qr = (r & 3) + 8 * (r >> 2) + 4 * half;
    const float il = __shfl(invl, qr, 64);
    const size_t row = (size_t)(b * SEQ + q0 + qr) * 1024 + hoff;
#pragma unroll
    for (int nf = 0; nf < 2; ++nf)
      ctx16[row + nf * 32 + l31] = cvt16(cf[nf][r] * il);
  }
}

// ---------------------------------------------------------------------------
// LayerNorm: out = LN(in + r1 + r2 + r3 + r4) * g + b; optional fp16 out.
// ---------------------------------------------------------------------------
__global__ __launch_bounds__(256)
void ln_kernel(const float* __restrict__ in, const float* __restrict__ r1,
               const float* __restrict__ r2, const float* __restrict__ r3,
               const float* __restrict__ r4,
               const float* __restrict__ g, const float* __restrict__ bt,
               float* __restrict__ outf, u16* __restrict__ outh)
{
  const int row = blockIdx.x, t = threadIdx.x;
  const size_t off = ((size_t)row << 10) + t * 4;
  float4 v = *(const float4*)&in[off];
  if (r1) { const float4 r = *(const float4*)&r1[off]; v.x += r.x; v.y += r.y; v.z += r.z; v.w += r.w; }
  if (r2) { const float4 r = *(const float4*)&r2[off]; v.x += r.x; v.y += r.y; v.z += r.z; v.w += r.w; }
  if (r3) { const float4 r = *(const float4*)&r3[off]; v.x += r.x; v.y += r.y; v.z += r.z; v.w += r.w; }
  if (r4) { const float4 r = *(const float4*)&r4[off]; v.x += r.x; v.y += r.y; v.z += r.z; v.w += r.w; }
  float s  = v.x + v.y + v.z + v.w;
  float ss = v.x * v.x + v.y * v.y + v.z * v.z + v.w * v.w;
#pragma unroll
  for (int o = 32; o; o >>= 1) {
    s  += __shfl_xor(s, o, 64);
    ss += __shfl_xor(ss, o, 64);
  }
  __shared__ float red[8];
  if ((t & 63) == 0) { red[(t >> 6) * 2] = s; red[(t >> 6) * 2 + 1] = ss; }
  __syncthreads();
  s  = red[0] + red[2] + red[4] + red[6];
  ss = red[1] + red[3] + red[5] + red[7];
  const float mu   = s * (1.f / 1024.f);
  const float var  = ss * (1.f / 1024.f) - mu * mu;
  const float rstd = rsqrtf(var + 1e-5f);
  const float4 gg = *(const float4*)&g[t * 4];
  const float4 bb = *(const float4*)&bt[t * 4];
  float4 o;
  o.x = (v.x - mu) * rstd * gg.x + bb.x;
  o.y = (v.y - mu) * rstd * gg.y + bb.y;
  o.z = (v.z - mu) * rstd * gg.z + bb.z;
  o.w = (v.w - mu) * rstd * gg.w + bb.w;
  if (outf) *(float4*)&outf[off] = o;
  if (outh) {
    union { u16 s[4]; u64 v64; } p;
    p.s[0] = cvt16(o.x); p.s[1] = cvt16(o.y); p.s[2] = cvt16(o.z); p.s[3] = cvt16(o.w);
    *(u64*)&outh[off] = p.v64;
  }
}

// ---------------------------------------------------------------------------
// MoE gate: probs[m, 0..7] = softmax(x[m,:] @ gate_w + gate_b). 1 wave / row.
// ---------------------------------------------------------------------------
__global__ __launch_bounds__(64)
void gate_kernel(const float* __restrict__ x, const float* __restrict__ gw,
                 const float* __restrict__ gb, float* __restrict__ probs)
{
  const int m = blockIdx.x, lane = threadIdx.x;
  float acc[8];
#pragma unroll
  for (int e = 0; e < 8; ++e) acc[e] = 0.f;
  for (int k = lane; k < 1024; k += 64) {
    const float xv = x[((size_t)m << 10) + k];
    const float4 g0 = *(const float4*)&gw[k * 8];
    const float4 g1 = *(const float4*)&gw[k * 8 + 4];
    acc[0] = __builtin_fmaf(xv, g0.x, acc[0]);
    acc[1] = __builtin_fmaf(xv, g0.y, acc[1]);
    acc[2] = __builtin_fmaf(xv, g0.z, acc[2]);
    acc[3] = __builtin_fmaf(xv, g0.w, acc[3]);
    acc[4] = __builtin_fmaf(xv, g1.x, acc[4]);
    acc[5] = __builtin_fmaf(xv, g1.y, acc[5]);
    acc[6] = __builtin_fmaf(xv, g1.z, acc[6]);
    acc[7] = __builtin_fmaf(xv, g1.w, acc[7]);
  }
#pragma unroll
  for (int o = 32; o; o >>= 1)
#pragma unroll
    for (int e = 0; e < 8; ++e) acc[e] += __shfl_xor(acc[e], o, 64);
  float lg[8], mx = -1e30f;
#pragma unroll
  for (int e = 0; e < 8; ++e) { lg[e] = acc[e] + gb[e]; mx = fmaxf(mx, lg[e]); }
  float se = 0.f;
#pragma unroll
  for (int e = 0; e < 8; ++e) { lg[e] = __expf(lg[e] - mx); se += lg[e]; }
  const float inv = 1.f / se;
  if (lane < 8) probs[(size_t)m * 8 + lane] = lg[lane] * inv;
}

// ---------------------------------------------------------------------------
extern "C" void kernel_launch(void* const* d_in, const int* in_sizes, int n_in,
                              void* d_out, int out_size, void* d_ws, size_t ws_size,
                              hipStream_t stream)
{
  const float* x      = (const float*)d_in[0];
  const float* conv_w = (const float*)d_in[1];
  const float* conv_b = (const float*)d_in[2];
  const float* wqkv   = (const float*)d_in[3];
  const float* bqkv   = (const float*)d_in[4];
  const float* wo     = (const float*)d_in[5];
  const float* bo     = (const float*)d_in[6];
  const float* ln1_g  = (const float*)d_in[7];
  const float* ln1_b  = (const float*)d_in[8];
  const float* gate_w = (const float*)d_in[9];
  const float* gate_b = (const float*)d_in[10];
  const float* w1     = (const float*)d_in[11];
  const float* b1     = (const float*)d_in[12];
  const float* w2     = (const float*)d_in[13];
  const float* b2     = (const float*)d_in[14];
  const float* ln2_g  = (const float*)d_in[15];
  const float* ln2_b  = (const float*)d_in[16];
  float* out = (float*)d_out;

  const dim3 blk256(256);
  char* W = (char*)d_ws;
#define MB(x) ((size_t)(x) << 20)
  // flat layout, no aliasing; peak 471 MiB (ws >= 481 MiB proven rounds 4-5).
  // ROUND-7 FIX: qkv16 is 24 MiB (4096x3072x2B), round 6 allocated 12 ->
  // QKV GEMM clobbered wo16/res1a -> absmax 5.58.  All regions re-spaced.
  float* x1_f   = (float*)(W + MB(0));     // 16 MiB
  float* moe_f  = (float*)(W + MB(16));    // 4 x 16 MiB
  float* probs  = (float*)(W + MB(80));    // 128 KiB
  u16* x1_h     = (u16*)(W + MB(81));      // 8 MiB
  u16* ctx16    = (u16*)(W + MB(89));      // 8 MiB
  u16* h16      = (u16*)(W + MB(97));      // 4 experts x 32 MiB = 128 MiB
  u16* im2c16   = (u16*)(W + MB(225));     // 24 MiB
  u16* wpk16    = (u16*)(W + MB(249));     // 6 MiB
  u16* wqkv16   = (u16*)(W + MB(255));     // 6 MiB
  float* yconv_f= (float*)(W + MB(261));   // 16 MiB
  u16* yconv16  = (u16*)(W + MB(277));     // 8 MiB
  u16* qkv16    = (u16*)(W + MB(285));     // 24 MiB  (285-309)
  u16* wo16     = (u16*)(W + MB(309));     // 2 MiB   (309-311)
  float* res1a  = (float*)(W + MB(311));   // 16 MiB  (311-327)
  float* res1b  = (float*)(W + MB(327));   // 16 MiB  (327-343)
  u16* w1s16    = (u16*)(W + MB(343));     // 64 MiB  (343-407)
  u16* w2s16    = (u16*)(W + MB(407));     // 64 MiB  (407-471)

  // ---- conversions (independent) ----
  im2c16_kernel<<<dim3(12288), blk256, 0, stream>>>(x, im2c16);
  wpk16_kernel<<<dim3(3072), blk256, 0, stream>>>(conv_w, wpk16);
  cvt_rows16_kernel<<<dim3(3072), blk256, 0, stream>>>(wqkv, wqkv16, 786432);
  cvt_rows16_kernel<<<dim3(1024), blk256, 0, stream>>>(wo, wo16, 262144);
  cvt_T16_kernel<<<dim3(128, 32, 8), dim3(32, 8), 0, stream>>>(w1, w1s16, 1024, 4096);
  cvt_T16_kernel<<<dim3(32, 128, 8), dim3(32, 8), 0, stream>>>(w2, w2s16, 4096, 1024);

  // ---- conv GEMM: (4096x3072)@(1024 rows x 3072)^T -> yconv f32+fp16 ----
  pgemm16_kernel<true, true><<<dim3(8, 32, 1), blk256, 0, stream>>>(
      im2c16, 3072, wpk16, 3072, 3072,
      yconv_f, yconv16, 1024,
      conv_b, nullptr, nullptr, 0, 0, 0, 0, 0, 0, 0, 0);

  // ---- QKV: (4096x1024)@(3072x1024)^T -> qkv16 ----
  pgemm16_kernel<false, true><<<dim3(24, 32, 1), blk256, 0, stream>>>(
      yconv16, 1024, wqkv16, 1024, 1024,
      nullptr, qkv16, 3072,
      bqkv, nullptr, nullptr, 0, 0, 0, 0, 0, 0, 0, 0);

  // ---- attention -> ctx16 ----
  attn16_kernel<<<dim3(SEQ / 128, NHEAD, NBAT), blk256, 0, stream>>>(qkv16, ctx16);

  // ---- out projection split-K2 -> res1a/res1b (bias+residual on z=1) ----
  pgemm16_kernel<true, false><<<dim3(8, 32, 2), blk256, 0, stream>>>(
      ctx16, 1024, wo16, 1024, 512,
      res1a, nullptr, 1024,
      bo, yconv_f, nullptr, 0, 0, 0,
      3, 512, 0, 4194304, 0);

  // ---- LN1 -> x1 f32 + fp16 ----
  ln_kernel<<<dim3(MTOT), blk256, 0, stream>>>(
      res1a, res1b, nullptr, nullptr, nullptr, ln1_g, ln1_b, x1_f, x1_h);

  // ---- gate ----
  gate_kernel<<<dim3(MTOT), dim3(64), 0, stream>>>(x1_f, gate_w, gate_b, probs);

  // ---- MoE experts 0-3 ----
  pgemm16_kernel<false, true><<<dim3(32, 32, 4), blk256, 0, stream>>>(
      x1_h, 1024, w1s16, 1024, 1024,
      nullptr, h16, 4096,
      b1, nullptr, nullptr, 0, 1 /*relu*/, 0,
      1, 0, 4194304, 16777216, 4096);
  pgemm16_kernel<true, false><<<dim3(8, 32, 4), blk256, 0, stream>>>(
      h16, 4096, w2s16, 4096, 4096,
      moe_f, nullptr, 1024,
      b2, nullptr, probs, 8, 0, 0 /*no accum*/,
      2, 16777216, 4194304, 4194304, 1024);

  // ---- MoE experts 4-7 (h16 reused; accum into moe_f) ----
  pgemm16_kernel<false, true><<<dim3(32, 32, 4), blk256, 0, stream>>>(
      x1_h, 1024, w1s16 + (size_t)4 * 4194304, 1024, 1024,
      nullptr, h16, 4096,
      b1 + 4 * 4096, nullptr, nullptr, 0, 1, 0,
      1, 0, 4194304, 16777216, 4096);
  pgemm16_kernel<true, false><<<dim3(8, 32, 4), blk256, 0, stream>>>(
      h16, 4096, w2s16 + (size_t)4 * 4194304, 4096, 4096,
      moe_f, nullptr, 1024,
      b2 + 4 * 1024, nullptr, probs + 4, 8, 0, 1 /*accum*/,
      2, 16777216, 4194304, 4194304, 1024);

  // ---- LN2(x1 + moe0..3) -> out ----
  ln_kernel<<<dim3(MTOT), blk256, 0, stream>>>(
      x1_f, moe_f, moe_f + 4194304, moe_f + 8388608, moe_f + 12582912,
      ln2_g, ln2_b, out, nullptr);
#undef MB
}